// Round 1
// baseline (4050.658 us; speedup 1.0000x reference)
//
#include <hip/hip_runtime.h>
#include <hip/hip_bf16.h>

#define N_NODES 100000
#define N_INCID 2000000
#define N_HEDGES 300000
#define IN_DIM 92
#define H_DIM 64
#define ATTR_DIM 35
#define HOUT_DIM 128
#define N_GRAPHS 512
#define N_LAYERS 3
#define MSG_DIM 163  // 2*H_DIM + ATTR_DIM

__device__ __forceinline__ float softplusf(float x) {
    // stable: max(x,0) + log1p(exp(-|x|))  (== jnp.logaddexp(x, 0))
    return fmaxf(x, 0.f) + log1pf(expf(-fabsf(x)));
}
__device__ __forceinline__ float sigmoidf(float x) {
    return 1.f / (1.f + expf(-x));
}

// h = x @ W_embed + b_embed ; 4 nodes per 256-thread block
__global__ void embed_k(const float* __restrict__ x, const float* __restrict__ W,
                        const float* __restrict__ b, float* __restrict__ h) {
    __shared__ float xs[4][IN_DIM];
    int node0 = blockIdx.x * 4;
    int t = threadIdx.x;
    for (int idx = t; idx < 4 * IN_DIM; idx += 256) {
        int r = idx / IN_DIM, c = idx % IN_DIM;
        int node = node0 + r;
        xs[r][c] = (node < N_NODES) ? x[node * IN_DIM + c] : 0.f;
    }
    __syncthreads();
    int r = t >> 6, d = t & 63;
    int node = node0 + r;
    if (node >= N_NODES) return;
    float acc = b[d];
#pragma unroll 4
    for (int k = 0; k < IN_DIM; ++k) acc += xs[r][k] * W[k * 64 + d];
    h[node * 64 + d] = acc;
}

__global__ void count_k(const int* __restrict__ inc_n, const int* __restrict__ inc_e,
                        int* __restrict__ ncnt, int* __restrict__ ecnt) {
    int i = blockIdx.x * 256 + threadIdx.x;
    if (i >= N_INCID) return;
    atomicAdd(&ncnt[inc_n[i]], 1);
    atomicAdd(&ecnt[inc_e[i]], 1);
}

__global__ void rcp_k(const int* __restrict__ cnt, float* __restrict__ rcp, int n) {
    int i = blockIdx.x * 256 + threadIdx.x;
    if (i < n) rcp[i] = 1.0f / (float)max(cnt[i], 1);
}

// node_asum[n] += hedge_attr[e]   (35 dims)
__global__ void attr_scatter_k(const int* __restrict__ inc_n, const int* __restrict__ inc_e,
                               const float* __restrict__ hattr, float* __restrict__ asum) {
    int idx = blockIdx.x * 256 + threadIdx.x;
    if (idx >= N_INCID * ATTR_DIM) return;
    int i = idx / ATTR_DIM, d = idx % ATTR_DIM;
    int n = inc_n[i], e = inc_e[i];
    atomicAdd(&asum[n * ATTR_DIM + d], hattr[e * ATTR_DIM + d]);
}

// hedge_sum[e] += h[n]   (one wave per incidence: d = lane)
__global__ void scatter_he_k(const int* __restrict__ inc_n, const int* __restrict__ inc_e,
                             const float* __restrict__ h, float* __restrict__ hsum) {
    int idx = blockIdx.x * 256 + threadIdx.x;
    int i = idx >> 6, d = idx & 63;
    if (i >= N_INCID) return;
    int n = inc_n[i], e = inc_e[i];
    atomicAdd(&hsum[e * 64 + d], h[n * 64 + d]);
}

// node_hsum[n] += hedge_sum[e] * hedge_rcp[e]
__global__ void scatter_nh_k(const int* __restrict__ inc_n, const int* __restrict__ inc_e,
                             const float* __restrict__ hsum, const float* __restrict__ ercp,
                             float* __restrict__ nhsum) {
    int idx = blockIdx.x * 256 + threadIdx.x;
    int i = idx >> 6, d = idx & 63;
    if (i >= N_INCID) return;
    int n = inc_n[i], e = inc_e[i];
    atomicAdd(&nhsum[n * 64 + d], hsum[e * 64 + d] * ercp[e]);
}

// per-node: z = [x_part, node_h, node_a] (163); h = softplus(sigmoid(z@Wf+bf)*softplus(z@Wc+bc)+h)
// 8 nodes per 256-thread block; each 64-lane group handles 2 nodes.
__global__ void layer_k(const float* __restrict__ Wf, const float* __restrict__ bfv,
                        const float* __restrict__ Wc, const float* __restrict__ bcv,
                        const int* __restrict__ ncnt, const float* __restrict__ nrcp,
                        const float* __restrict__ nhsum, const float* __restrict__ asum,
                        float* __restrict__ h) {
    __shared__ float zs[8][MSG_DIM];
    int node0 = blockIdx.x * 8;
    int t = threadIdx.x;
    for (int idx = t; idx < 8 * MSG_DIM; idx += 256) {
        int r = idx / MSG_DIM, c = idx % MSG_DIM;
        int node = node0 + r;
        float v = 0.f;
        if (node < N_NODES) {
            float rc = nrcp[node];
            if (c < 64)       v = (ncnt[node] > 0) ? h[node * 64 + c] : 0.f;
            else if (c < 128) v = nhsum[node * 64 + (c - 64)] * rc;
            else              v = asum[node * ATTR_DIM + (c - 128)] * rc;
        }
        zs[r][c] = v;
    }
    __syncthreads();
    int d = t & 63, g = t >> 6;
    int r0 = g * 2, r1 = g * 2 + 1;
    float f0 = 0, f1 = 0, c0 = 0, c1 = 0;
#pragma unroll 4
    for (int k = 0; k < MSG_DIM; ++k) {
        float wf = Wf[k * 64 + d], wc = Wc[k * 64 + d];
        float z0 = zs[r0][k], z1 = zs[r1][k];
        f0 += z0 * wf; f1 += z1 * wf;
        c0 += z0 * wc; c1 += z1 * wc;
    }
    float bfd = bfv[d], bcd = bcv[d];
    int n0 = node0 + r0, n1 = node0 + r1;
    if (n0 < N_NODES) {
        float hv = h[n0 * 64 + d];
        h[n0 * 64 + d] = softplusf(sigmoidf(f0 + bfd) * softplusf(c0 + bcd) + hv);
    }
    if (n1 < N_NODES) {
        float hv = h[n1 * 64 + d];
        h[n1 * 64 + d] = softplusf(sigmoidf(f1 + bfd) * softplusf(c1 + bcd) + hv);
    }
}

__global__ void pool_scatter_k(const float* __restrict__ h, const int* __restrict__ batch,
                               float* __restrict__ psum, int* __restrict__ gcnt) {
    int idx = blockIdx.x * 256 + threadIdx.x;
    int n = idx >> 6, d = idx & 63;
    if (n >= N_NODES) return;
    int g = batch[n];
    atomicAdd(&psum[g * 64 + d], h[n * 64 + d]);
    if (d == 0) atomicAdd(&gcnt[g], 1);
}

// per-graph head: p = softplus(pooled@W_proj+b_proj); out = p@W_out + b_out
__global__ void head_k(const float* __restrict__ psum, const int* __restrict__ gcnt,
                       const float* __restrict__ Wp, const float* __restrict__ bp,
                       const float* __restrict__ Wo, const float* __restrict__ bo,
                       float* __restrict__ out) {
    __shared__ float pm[64];
    __shared__ float pr[128];
    int g = blockIdx.x, t = threadIdx.x;
    float rc = 1.0f / fmaxf((float)gcnt[g], 1.0f);
    if (t < 64) pm[t] = psum[g * 64 + t] * rc;
    __syncthreads();
    float acc = bp[t];
#pragma unroll 4
    for (int k = 0; k < 64; ++k) acc += pm[k] * Wp[k * HOUT_DIM + t];
    pr[t] = softplusf(acc) * Wo[t];
    __syncthreads();
    for (int s = 64; s > 0; s >>= 1) {
        if (t < s) pr[t] += pr[t + s];
        __syncthreads();
    }
    if (t == 0) out[g] = pr[0] + bo[0];
}

extern "C" void kernel_launch(void* const* d_in, const int* in_sizes, int n_in,
                              void* d_out, int out_size, void* d_ws, size_t ws_size,
                              hipStream_t stream) {
    const float* x       = (const float*)d_in[0];
    const int*   inc_n   = (const int*)d_in[1];
    const int*   inc_e   = (const int*)d_in[2];
    const float* hattr   = (const float*)d_in[3];
    const int*   batch   = (const int*)d_in[4];
    const float* W_embed = (const float*)d_in[5];
    const float* b_embed = (const float*)d_in[6];
    const float* Wf      = (const float*)d_in[7];
    const float* bf      = (const float*)d_in[8];
    const float* Wc      = (const float*)d_in[9];
    const float* bc      = (const float*)d_in[10];
    const float* W_proj  = (const float*)d_in[11];
    const float* b_proj  = (const float*)d_in[12];
    const float* W_out   = (const float*)d_in[13];
    const float* b_out   = (const float*)d_in[14];
    float* out = (float*)d_out;

    char* ws = (char*)d_ws;
    size_t off = 0;
    auto alloc = [&](size_t bytes) {
        void* p = ws + off;
        off = (off + bytes + 255) & ~(size_t)255;
        return p;
    };
    float* h     = (float*)alloc((size_t)N_NODES * 64 * 4);
    float* hsum  = (float*)alloc((size_t)N_HEDGES * 64 * 4);
    float* nhsum = (float*)alloc((size_t)N_NODES * 64 * 4);
    float* asum  = (float*)alloc((size_t)N_NODES * ATTR_DIM * 4);
    int*   ncnt  = (int*)alloc((size_t)N_NODES * 4);
    int*   ecnt  = (int*)alloc((size_t)N_HEDGES * 4);
    float* nrcp  = (float*)alloc((size_t)N_NODES * 4);
    float* ercp  = (float*)alloc((size_t)N_HEDGES * 4);
    float* psum  = (float*)alloc((size_t)N_GRAPHS * 64 * 4);
    int*   gcnt  = (int*)alloc((size_t)N_GRAPHS * 4);

    hipMemsetAsync(ncnt, 0, (size_t)N_NODES * 4, stream);
    hipMemsetAsync(ecnt, 0, (size_t)N_HEDGES * 4, stream);
    hipMemsetAsync(asum, 0, (size_t)N_NODES * ATTR_DIM * 4, stream);
    hipMemsetAsync(psum, 0, (size_t)N_GRAPHS * 64 * 4, stream);
    hipMemsetAsync(gcnt, 0, (size_t)N_GRAPHS * 4, stream);

    embed_k<<<(N_NODES + 3) / 4, 256, 0, stream>>>(x, W_embed, b_embed, h);
    count_k<<<(N_INCID + 255) / 256, 256, 0, stream>>>(inc_n, inc_e, ncnt, ecnt);
    rcp_k<<<(N_NODES + 255) / 256, 256, 0, stream>>>(ncnt, nrcp, N_NODES);
    rcp_k<<<(N_HEDGES + 255) / 256, 256, 0, stream>>>(ecnt, ercp, N_HEDGES);
    attr_scatter_k<<<(N_INCID * ATTR_DIM + 255) / 256, 256, 0, stream>>>(inc_n, inc_e, hattr, asum);

    for (int l = 0; l < N_LAYERS; ++l) {
        hipMemsetAsync(hsum, 0, (size_t)N_HEDGES * 64 * 4, stream);
        hipMemsetAsync(nhsum, 0, (size_t)N_NODES * 64 * 4, stream);
        scatter_he_k<<<(N_INCID * 64) / 256, 256, 0, stream>>>(inc_n, inc_e, h, hsum);
        scatter_nh_k<<<(N_INCID * 64) / 256, 256, 0, stream>>>(inc_n, inc_e, hsum, ercp, nhsum);
        layer_k<<<(N_NODES + 7) / 8, 256, 0, stream>>>(Wf + (size_t)l * MSG_DIM * 64, bf + l * 64,
                                                       Wc + (size_t)l * MSG_DIM * 64, bc + l * 64,
                                                       ncnt, nrcp, nhsum, asum, h);
    }
    pool_scatter_k<<<(N_NODES * 64 + 255) / 256, 256, 0, stream>>>(h, batch, psum, gcnt);
    head_k<<<N_GRAPHS, 128, 0, stream>>>(psum, gcnt, W_proj, b_proj, W_out, b_out, out);
}

// Round 2
// 2445.430 us; speedup vs baseline: 1.6564x; 1.6564x over previous
//
#include <hip/hip_runtime.h>
#include <hip/hip_bf16.h>

#define N_NODES 100000
#define N_INCID 2000000
#define N_HEDGES 300000
#define IN_DIM 92
#define H_DIM 64
#define ATTR_DIM 35
#define HOUT_DIM 128
#define N_GRAPHS 512
#define N_LAYERS 3
#define MSG_DIM 163  // 2*H_DIM + ATTR_DIM

__device__ __forceinline__ float softplusf(float x) {
    return fmaxf(x, 0.f) + log1pf(expf(-fabsf(x)));
}
__device__ __forceinline__ float sigmoidf(float x) {
    return 1.f / (1.f + expf(-x));
}

// ---------- embed: h = x @ W_embed + b ----------
__global__ void embed_k(const float* __restrict__ x, const float* __restrict__ W,
                        const float* __restrict__ b, float* __restrict__ h) {
    __shared__ float xs[4][IN_DIM];
    int node0 = blockIdx.x * 4;
    int t = threadIdx.x;
    for (int idx = t; idx < 4 * IN_DIM; idx += 256) {
        int r = idx / IN_DIM, c = idx % IN_DIM;
        int node = node0 + r;
        xs[r][c] = (node < N_NODES) ? x[node * IN_DIM + c] : 0.f;
    }
    __syncthreads();
    int r = t >> 6, d = t & 63;
    int node = node0 + r;
    if (node >= N_NODES) return;
    float acc = b[d];
#pragma unroll 4
    for (int k = 0; k < IN_DIM; ++k) acc += xs[r][k] * W[k * 64 + d];
    h[node * 64 + d] = acc;
}

// ---------- degree counts ----------
__global__ void count_k(const int* __restrict__ inc_n, const int* __restrict__ inc_e,
                        int* __restrict__ ncnt, int* __restrict__ ecnt) {
    int i = blockIdx.x * 256 + threadIdx.x;
    if (i >= N_INCID) return;
    atomicAdd(&ncnt[inc_n[i]], 1);
    atomicAdd(&ecnt[inc_e[i]], 1);
}

__global__ void rcp_k(const int* __restrict__ cnt, float* __restrict__ rcp, int n) {
    int i = blockIdx.x * 256 + threadIdx.x;
    if (i < n) rcp[i] = 1.0f / (float)max(cnt[i], 1);
}

// ---------- generic exclusive scan (3-kernel) ----------
__global__ void scan1_k(const int* __restrict__ in, int* __restrict__ out,
                        int* __restrict__ bsum, int n) {
    __shared__ int tmp[256];
    int gid = blockIdx.x * 256 + threadIdx.x;
    int v = (gid < n) ? in[gid] : 0;
    tmp[threadIdx.x] = v;
    __syncthreads();
    for (int o = 1; o < 256; o <<= 1) {
        int t = (threadIdx.x >= o) ? tmp[threadIdx.x - o] : 0;
        __syncthreads();
        tmp[threadIdx.x] += t;
        __syncthreads();
    }
    if (gid < n) out[gid] = tmp[threadIdx.x] - v;  // exclusive
    if (threadIdx.x == 255) bsum[blockIdx.x] = tmp[255];
}

__global__ void scan2_k(int* __restrict__ bsum, int nb) {
    __shared__ int tmp[256];
    __shared__ int carry;
    if (threadIdx.x == 0) carry = 0;
    __syncthreads();
    for (int base = 0; base < nb; base += 256) {
        int gid = base + threadIdx.x;
        int v = (gid < nb) ? bsum[gid] : 0;
        tmp[threadIdx.x] = v;
        __syncthreads();
        for (int o = 1; o < 256; o <<= 1) {
            int t = (threadIdx.x >= o) ? tmp[threadIdx.x - o] : 0;
            __syncthreads();
            tmp[threadIdx.x] += t;
            __syncthreads();
        }
        if (gid < nb) bsum[gid] = tmp[threadIdx.x] - v + carry;  // exclusive block offset
        __syncthreads();
        if (threadIdx.x == 0) carry += tmp[255];
        __syncthreads();
    }
}

__global__ void scan3_k(int* __restrict__ out, const int* __restrict__ bsum, int n) {
    int gid = blockIdx.x * 256 + threadIdx.x;
    if (gid < n) out[gid] += bsum[blockIdx.x];
}

__global__ void sentinel_k(int* __restrict__ eoff, int* __restrict__ noff) {
    if (threadIdx.x == 0) eoff[N_HEDGES] = N_INCID;
    if (threadIdx.x == 1) noff[N_NODES] = N_INCID;
}

// ---------- CSR fill (counting sort placement; intra-segment order nondeterministic,
// only affects f32 sum rounding ~1e-6, far under threshold) ----------
__global__ void fill_k(const int* __restrict__ inc_n, const int* __restrict__ inc_e,
                       const int* __restrict__ eoff, int* __restrict__ ecur, int* __restrict__ csr_en,
                       const int* __restrict__ noff, int* __restrict__ ncur, int* __restrict__ csr_ne) {
    int i = blockIdx.x * 256 + threadIdx.x;
    if (i >= N_INCID) return;
    int n = inc_n[i], e = inc_e[i];
    int pe = eoff[e] + atomicAdd(&ecur[e], 1);
    csr_en[pe] = n;
    int pn = noff[n] + atomicAdd(&ncur[n], 1);
    csr_ne[pn] = e;
}

// ---------- per-hedge mean of member node features (wave per hedge, lane = dim) ----------
__global__ void hmean_k(const int* __restrict__ eoff, const int* __restrict__ csr_en,
                        const float* __restrict__ h, const float* __restrict__ ercp,
                        float* __restrict__ hmean) {
    int idx = blockIdx.x * 256 + threadIdx.x;
    int e = idx >> 6, d = idx & 63;
    if (e >= N_HEDGES) return;
    int s = eoff[e], t = eoff[e + 1];
    float acc = 0.f;
    for (int k = s; k < t; ++k) acc += h[csr_en[k] * 64 + d];
    hmean[e * 64 + d] = acc * ercp[e];
}

// ---------- per-node mean over incident hedges of hmean (wave per node) ----------
__global__ void nodeh_k(const int* __restrict__ noff, const int* __restrict__ csr_ne,
                        const float* __restrict__ hmean, const float* __restrict__ nrcp,
                        float* __restrict__ nh) {
    int idx = blockIdx.x * 256 + threadIdx.x;
    int n = idx >> 6, d = idx & 63;
    if (n >= N_NODES) return;
    int s = noff[n], t = noff[n + 1];
    float acc = 0.f;
    for (int k = s; k < t; ++k) acc += hmean[csr_ne[k] * 64 + d];
    nh[n * 64 + d] = acc * nrcp[n];
}

// ---------- per-node mean of hedge_attr (one-time; wave per node, lanes 0..34) ----------
__global__ void nodea_k(const int* __restrict__ noff, const int* __restrict__ csr_ne,
                        const float* __restrict__ hattr, const float* __restrict__ nrcp,
                        float* __restrict__ na) {
    int idx = blockIdx.x * 256 + threadIdx.x;
    int n = idx >> 6, lane = idx & 63;
    if (n >= N_NODES || lane >= ATTR_DIM) return;
    int s = noff[n], t = noff[n + 1];
    float acc = 0.f;
    for (int k = s; k < t; ++k) acc += hattr[csr_ne[k] * ATTR_DIM + lane];
    na[n * ATTR_DIM + lane] = acc * nrcp[n];
}

// ---------- per-node fused gate/core GEMV + activation ----------
__global__ void layer_k(const float* __restrict__ Wf, const float* __restrict__ bfv,
                        const float* __restrict__ Wc, const float* __restrict__ bcv,
                        const int* __restrict__ ncnt, const float* __restrict__ nh,
                        const float* __restrict__ na, float* __restrict__ h) {
    __shared__ float zs[8][MSG_DIM];
    int node0 = blockIdx.x * 8;
    int t = threadIdx.x;
    for (int idx = t; idx < 8 * MSG_DIM; idx += 256) {
        int r = idx / MSG_DIM, c = idx % MSG_DIM;
        int node = node0 + r;
        float v = 0.f;
        if (node < N_NODES) {
            if (c < 64)       v = (ncnt[node] > 0) ? h[node * 64 + c] : 0.f;
            else if (c < 128) v = nh[node * 64 + (c - 64)];
            else              v = na[node * ATTR_DIM + (c - 128)];
        }
        zs[r][c] = v;
    }
    __syncthreads();
    int d = t & 63, g = t >> 6;
    int r0 = g * 2, r1 = g * 2 + 1;
    float f0 = 0, f1 = 0, c0 = 0, c1 = 0;
#pragma unroll 4
    for (int k = 0; k < MSG_DIM; ++k) {
        float wf = Wf[k * 64 + d], wc = Wc[k * 64 + d];
        float z0 = zs[r0][k], z1 = zs[r1][k];
        f0 += z0 * wf; f1 += z1 * wf;
        c0 += z0 * wc; c1 += z1 * wc;
    }
    float bfd = bfv[d], bcd = bcv[d];
    int n0 = node0 + r0, n1 = node0 + r1;
    if (n0 < N_NODES) {
        float hv = h[n0 * 64 + d];
        h[n0 * 64 + d] = softplusf(sigmoidf(f0 + bfd) * softplusf(c0 + bcd) + hv);
    }
    if (n1 < N_NODES) {
        float hv = h[n1 * 64 + d];
        h[n1 * 64 + d] = softplusf(sigmoidf(f1 + bfd) * softplusf(c1 + bcd) + hv);
    }
}

// ---------- per-graph boundaries in sorted batch ----------
__global__ void gstart_k(const int* __restrict__ batch, int* __restrict__ gstart) {
    int g = blockIdx.x * 256 + threadIdx.x;
    if (g > N_GRAPHS) return;
    int lo = 0, hi = N_NODES;
    while (lo < hi) {
        int mid = (lo + hi) >> 1;
        if (batch[mid] < g) lo = mid + 1; else hi = mid;
    }
    gstart[g] = lo;
}

// ---------- fused pool (mean over contiguous node range) + proj + out ----------
__global__ void poolhead_k(const float* __restrict__ h, const int* __restrict__ gstart,
                           const float* __restrict__ Wp, const float* __restrict__ bp,
                           const float* __restrict__ Wo, const float* __restrict__ bo,
                           float* __restrict__ out) {
    __shared__ float partial[4][64];
    __shared__ float pm[64];
    __shared__ float pr[128];
    int g = blockIdx.x, t = threadIdx.x;
    int s = gstart[g], e = gstart[g + 1];
    int w = t >> 6, lane = t & 63;
    float acc = 0.f;
    for (int n = s + w; n < e; n += 4) acc += h[n * 64 + lane];
    partial[w][lane] = acc;
    __syncthreads();
    if (t < 64) {
        float c = fmaxf((float)(e - s), 1.0f);
        pm[t] = (partial[0][t] + partial[1][t] + partial[2][t] + partial[3][t]) / c;
    }
    __syncthreads();
    if (t < 128) {
        float a = bp[t];
#pragma unroll 4
        for (int k = 0; k < 64; ++k) a += pm[k] * Wp[k * HOUT_DIM + t];
        pr[t] = softplusf(a) * Wo[t];
    }
    __syncthreads();
    if (t < 64) {
        float v = pr[t] + pr[t + 64];
        for (int o = 32; o > 0; o >>= 1) v += __shfl_down(v, o);
        if (t == 0) out[g] = v + bo[0];
    }
}

extern "C" void kernel_launch(void* const* d_in, const int* in_sizes, int n_in,
                              void* d_out, int out_size, void* d_ws, size_t ws_size,
                              hipStream_t stream) {
    const float* x       = (const float*)d_in[0];
    const int*   inc_n   = (const int*)d_in[1];
    const int*   inc_e   = (const int*)d_in[2];
    const float* hattr   = (const float*)d_in[3];
    const int*   batch   = (const int*)d_in[4];
    const float* W_embed = (const float*)d_in[5];
    const float* b_embed = (const float*)d_in[6];
    const float* Wf      = (const float*)d_in[7];
    const float* bf      = (const float*)d_in[8];
    const float* Wc      = (const float*)d_in[9];
    const float* bc      = (const float*)d_in[10];
    const float* W_proj  = (const float*)d_in[11];
    const float* b_proj  = (const float*)d_in[12];
    const float* W_out   = (const float*)d_in[13];
    const float* b_out   = (const float*)d_in[14];
    float* out = (float*)d_out;

    char* ws = (char*)d_ws;
    size_t off = 0;
    auto alloc = [&](size_t bytes) {
        void* p = ws + off;
        off = (off + bytes + 255) & ~(size_t)255;
        return p;
    };
    float* h      = (float*)alloc((size_t)N_NODES * 64 * 4);
    float* hmean  = (float*)alloc((size_t)N_HEDGES * 64 * 4);
    float* nh     = (float*)alloc((size_t)N_NODES * 64 * 4);
    float* na     = (float*)alloc((size_t)N_NODES * ATTR_DIM * 4);
    int*   ncnt   = (int*)alloc((size_t)N_NODES * 4);
    int*   ecnt   = (int*)alloc((size_t)N_HEDGES * 4);
    float* nrcp   = (float*)alloc((size_t)N_NODES * 4);
    float* ercp   = (float*)alloc((size_t)N_HEDGES * 4);
    int*   eoff   = (int*)alloc((size_t)(N_HEDGES + 1) * 4);
    int*   noff   = (int*)alloc((size_t)(N_NODES + 1) * 4);
    int*   ecur   = (int*)alloc((size_t)N_HEDGES * 4);
    int*   ncur   = (int*)alloc((size_t)N_NODES * 4);
    int*   csr_en = (int*)alloc((size_t)N_INCID * 4);
    int*   csr_ne = (int*)alloc((size_t)N_INCID * 4);
    int*   bsum   = (int*)alloc((size_t)2048 * 4);
    int*   gstart = (int*)alloc((size_t)(N_GRAPHS + 1) * 4);

    hipMemsetAsync(ncnt, 0, (size_t)N_NODES * 4, stream);
    hipMemsetAsync(ecnt, 0, (size_t)N_HEDGES * 4, stream);
    hipMemsetAsync(ecur, 0, (size_t)N_HEDGES * 4, stream);
    hipMemsetAsync(ncur, 0, (size_t)N_NODES * 4, stream);

    embed_k<<<(N_NODES + 3) / 4, 256, 0, stream>>>(x, W_embed, b_embed, h);
    count_k<<<(N_INCID + 255) / 256, 256, 0, stream>>>(inc_n, inc_e, ncnt, ecnt);
    rcp_k<<<(N_NODES + 255) / 256, 256, 0, stream>>>(ncnt, nrcp, N_NODES);
    rcp_k<<<(N_HEDGES + 255) / 256, 256, 0, stream>>>(ecnt, ercp, N_HEDGES);

    // exclusive scans: ecnt -> eoff, ncnt -> noff
    {
        int nbE = (N_HEDGES + 255) / 256;
        scan1_k<<<nbE, 256, 0, stream>>>(ecnt, eoff, bsum, N_HEDGES);
        scan2_k<<<1, 256, 0, stream>>>(bsum, nbE);
        scan3_k<<<nbE, 256, 0, stream>>>(eoff, bsum, N_HEDGES);
        int nbN = (N_NODES + 255) / 256;
        scan1_k<<<nbN, 256, 0, stream>>>(ncnt, noff, bsum, N_NODES);
        scan2_k<<<1, 256, 0, stream>>>(bsum, nbN);
        scan3_k<<<nbN, 256, 0, stream>>>(noff, bsum, N_NODES);
        sentinel_k<<<1, 64, 0, stream>>>(eoff, noff);
    }
    fill_k<<<(N_INCID + 255) / 256, 256, 0, stream>>>(inc_n, inc_e, eoff, ecur, csr_en,
                                                      noff, ncur, csr_ne);
    nodea_k<<<(N_NODES * 64 + 255) / 256, 256, 0, stream>>>(noff, csr_ne, hattr, nrcp, na);

    for (int l = 0; l < N_LAYERS; ++l) {
        hmean_k<<<(N_HEDGES * 64 + 255) / 256, 256, 0, stream>>>(eoff, csr_en, h, ercp, hmean);
        nodeh_k<<<(N_NODES * 64 + 255) / 256, 256, 0, stream>>>(noff, csr_ne, hmean, nrcp, nh);
        layer_k<<<(N_NODES + 7) / 8, 256, 0, stream>>>(Wf + (size_t)l * MSG_DIM * 64, bf + l * 64,
                                                       Wc + (size_t)l * MSG_DIM * 64, bc + l * 64,
                                                       ncnt, nh, na, h);
    }
    gstart_k<<<(N_GRAPHS + 1 + 255) / 256, 256, 0, stream>>>(batch, gstart);
    poolhead_k<<<N_GRAPHS, 256, 0, stream>>>(h, gstart, W_proj, b_proj, W_out, b_out, out);
}

// Round 3
// 1776.711 us; speedup vs baseline: 2.2799x; 1.3764x over previous
//
#include <hip/hip_runtime.h>
#include <hip/hip_bf16.h>

#define N_NODES 100000
#define N_INCID 2000000
#define N_HEDGES 300000
#define IN_DIM 92
#define H_DIM 64
#define ATTR_DIM 35
#define ATTR_PAIRS 18  // padded to 36 dims
#define HOUT_DIM 128
#define N_GRAPHS 512
#define N_LAYERS 3
#define MSG_DIM 163     // 2*H_DIM + ATTR_DIM
#define ZS_STRIDE 168   // padded LDS row stride (672B, 16B-aligned)

__device__ __forceinline__ float softplusf(float x) {
    return fmaxf(x, 0.f) + log1pf(expf(-fabsf(x)));
}
__device__ __forceinline__ float sigmoidf(float x) {
    return 1.f / (1.f + expf(-x));
}
// packed bf16 pair <-> float2 (hand-rolled, RN)
__device__ __forceinline__ float2 bf2_to_f2(unsigned v) {
    union { unsigned u; float f; } a, b;
    a.u = v << 16;
    b.u = v & 0xffff0000u;
    return make_float2(a.f, b.f);
}
__device__ __forceinline__ unsigned f2_to_bf2(float x, float y) {
    union { float f; unsigned u; } a, b;
    a.f = x; b.f = y;
    unsigned lo = (a.u + 0x7fffu + ((a.u >> 16) & 1u)) >> 16;
    unsigned hi = ((b.u + 0x7fffu + ((b.u >> 16) & 1u)) >> 16) << 16;
    return lo | hi;
}

// ---------- embed: h = x @ W_embed + b ; writes f32 h + bf16 mirror hb ----------
__global__ void embed_k(const float* __restrict__ x, const float* __restrict__ W,
                        const float* __restrict__ b, float* __restrict__ h,
                        unsigned* __restrict__ hb) {
    __shared__ float xs[4][IN_DIM];
    int node0 = blockIdx.x * 4;
    int t = threadIdx.x;
    for (int idx = t; idx < 4 * IN_DIM; idx += 256) {
        int r = idx / IN_DIM, c = idx % IN_DIM;
        int node = node0 + r;
        xs[r][c] = (node < N_NODES) ? x[node * IN_DIM + c] : 0.f;
    }
    __syncthreads();
    int r = t >> 6, d = t & 63;
    int node = node0 + r;
    if (node >= N_NODES) return;
    float acc = b[d];
#pragma unroll 4
    for (int k = 0; k < IN_DIM; ++k) acc += xs[r][k] * W[k * 64 + d];
    h[node * 64 + d] = acc;
    float other = __shfl_xor(acc, 1);
    if ((d & 1) == 0) hb[node * 32 + (d >> 1)] = f2_to_bf2(acc, other);
}

// ---------- hattr -> bf16 padded mirror ----------
__global__ void attrconv_k(const float* __restrict__ hattr, unsigned* __restrict__ hab) {
    int idx = blockIdx.x * 256 + threadIdx.x;
    if (idx >= N_HEDGES * ATTR_PAIRS) return;
    int e = idx / ATTR_PAIRS, p = idx - e * ATTR_PAIRS;
    int d0 = 2 * p, d1 = 2 * p + 1;
    float v0 = hattr[e * ATTR_DIM + d0];
    float v1 = (d1 < ATTR_DIM) ? hattr[e * ATTR_DIM + d1] : 0.f;
    hab[idx] = f2_to_bf2(v0, v1);
}

// ---------- degree counts ----------
__global__ void count_k(const int* __restrict__ inc_n, const int* __restrict__ inc_e,
                        int* __restrict__ ncnt, int* __restrict__ ecnt) {
    int i = blockIdx.x * 256 + threadIdx.x;
    if (i >= N_INCID) return;
    atomicAdd(&ncnt[inc_n[i]], 1);
    atomicAdd(&ecnt[inc_e[i]], 1);
}

__global__ void rcp_k(const int* __restrict__ cnt, float* __restrict__ rcp, int n) {
    int i = blockIdx.x * 256 + threadIdx.x;
    if (i < n) rcp[i] = 1.0f / (float)max(cnt[i], 1);
}

// ---------- exclusive scan (3-kernel) ----------
__global__ void scan1_k(const int* __restrict__ in, int* __restrict__ out,
                        int* __restrict__ bsum, int n) {
    __shared__ int tmp[256];
    int gid = blockIdx.x * 256 + threadIdx.x;
    int v = (gid < n) ? in[gid] : 0;
    tmp[threadIdx.x] = v;
    __syncthreads();
    for (int o = 1; o < 256; o <<= 1) {
        int t = (threadIdx.x >= o) ? tmp[threadIdx.x - o] : 0;
        __syncthreads();
        tmp[threadIdx.x] += t;
        __syncthreads();
    }
    if (gid < n) out[gid] = tmp[threadIdx.x] - v;
    if (threadIdx.x == 255) bsum[blockIdx.x] = tmp[255];
}

__global__ void scan2_k(int* __restrict__ bsum, int nb) {
    __shared__ int tmp[256];
    __shared__ int carry;
    if (threadIdx.x == 0) carry = 0;
    __syncthreads();
    for (int base = 0; base < nb; base += 256) {
        int gid = base + threadIdx.x;
        int v = (gid < nb) ? bsum[gid] : 0;
        tmp[threadIdx.x] = v;
        __syncthreads();
        for (int o = 1; o < 256; o <<= 1) {
            int t = (threadIdx.x >= o) ? tmp[threadIdx.x - o] : 0;
            __syncthreads();
            tmp[threadIdx.x] += t;
            __syncthreads();
        }
        if (gid < nb) bsum[gid] = tmp[threadIdx.x] - v + carry;
        __syncthreads();
        if (threadIdx.x == 0) carry += tmp[255];
        __syncthreads();
    }
}

__global__ void scan3_k(int* __restrict__ out, const int* __restrict__ bsum, int n) {
    int gid = blockIdx.x * 256 + threadIdx.x;
    if (gid < n) out[gid] += bsum[blockIdx.x];
}

__global__ void sentinel_k(int* __restrict__ eoff, int* __restrict__ noff) {
    if (threadIdx.x == 0) eoff[N_HEDGES] = N_INCID;
    if (threadIdx.x == 1) noff[N_NODES] = N_INCID;
}

// ---------- CSR fill ----------
__global__ void fill_k(const int* __restrict__ inc_n, const int* __restrict__ inc_e,
                       const int* __restrict__ eoff, int* __restrict__ ecur, int* __restrict__ csr_en,
                       const int* __restrict__ noff, int* __restrict__ ncur, int* __restrict__ csr_ne) {
    int i = blockIdx.x * 256 + threadIdx.x;
    if (i >= N_INCID) return;
    int n = inc_n[i], e = inc_e[i];
    int pe = eoff[e] + atomicAdd(&ecur[e], 1);
    csr_en[pe] = n;
    int pn = noff[n] + atomicAdd(&ncur[n], 1);
    csr_ne[pn] = e;
}

// ---------- per-hedge mean of member node features (bf16 in, bf16 out) ----------
// 32 lanes per hedge, lane owns a bf16 pair
__global__ void hmean_k(const int* __restrict__ eoff, const int* __restrict__ csr_en,
                        const unsigned* __restrict__ hb, const float* __restrict__ ercp,
                        unsigned* __restrict__ hmean) {
    int idx = blockIdx.x * 256 + threadIdx.x;
    int e = idx >> 5, p = idx & 31;
    if (e >= N_HEDGES) return;
    int s = eoff[e], t = eoff[e + 1];
    float a0 = 0.f, a1 = 0.f;
    for (int k = s; k < t; ++k) {
        float2 f = bf2_to_f2(hb[csr_en[k] * 32 + p]);
        a0 += f.x; a1 += f.y;
    }
    float rc = ercp[e];
    hmean[e * 32 + p] = f2_to_bf2(a0 * rc, a1 * rc);
}

// ---------- per-node mean of hmean over incident hedges (bf16 in, f32 out) ----------
__global__ void nodeh_k(const int* __restrict__ noff, const int* __restrict__ csr_ne,
                        const unsigned* __restrict__ hmean, const float* __restrict__ nrcp,
                        float2* __restrict__ nh2) {
    int idx = blockIdx.x * 256 + threadIdx.x;
    int n = idx >> 5, p = idx & 31;
    if (n >= N_NODES) return;
    int s = noff[n], t = noff[n + 1];
    float a0 = 0.f, a1 = 0.f;
    for (int k = s; k < t; ++k) {
        float2 f = bf2_to_f2(hmean[csr_ne[k] * 32 + p]);
        a0 += f.x; a1 += f.y;
    }
    float rc = nrcp[n];
    nh2[n * 32 + p] = make_float2(a0 * rc, a1 * rc);
}

// ---------- per-node mean of hedge_attr (bf16 in, f32 out; one-time) ----------
__global__ void nodea_k(const int* __restrict__ noff, const int* __restrict__ csr_ne,
                        const unsigned* __restrict__ hab, const float* __restrict__ nrcp,
                        float* __restrict__ na) {
    int idx = blockIdx.x * 256 + threadIdx.x;
    int n = idx >> 5, p = idx & 31;
    if (n >= N_NODES || p >= ATTR_PAIRS) return;
    int s = noff[n], t = noff[n + 1];
    float a0 = 0.f, a1 = 0.f;
    for (int k = s; k < t; ++k) {
        float2 f = bf2_to_f2(hab[csr_ne[k] * ATTR_PAIRS + p]);
        a0 += f.x; a1 += f.y;
    }
    float rc = nrcp[n];
    int d0 = 2 * p;
    na[n * ATTR_DIM + d0] = a0 * rc;
    if (d0 + 1 < ATTR_DIM) na[n * ATTR_DIM + d0 + 1] = a1 * rc;
}

// ---------- fused gate/core GEMV + activation; 32 nodes/block, 8 nodes/wave ----------
__global__ void layer_k(const float* __restrict__ Wf, const float* __restrict__ bfv,
                        const float* __restrict__ Wc, const float* __restrict__ bcv,
                        const int* __restrict__ ncnt, const float* __restrict__ nh,
                        const float* __restrict__ na, float* __restrict__ h,
                        unsigned* __restrict__ hb) {
    __shared__ float zs[32][ZS_STRIDE];
    int node0 = blockIdx.x * 32;  // N_NODES % 32 == 0
    int t = threadIdx.x;
    for (int idx = t; idx < 32 * MSG_DIM; idx += 256) {
        int r = idx / MSG_DIM, c = idx - r * MSG_DIM;
        int node = node0 + r;
        float v;
        if (c < 64)       v = (ncnt[node] > 0) ? h[node * 64 + c] : 0.f;
        else if (c < 128) v = nh[node * 64 + (c - 64)];
        else              v = na[node * ATTR_DIM + (c - 128)];
        zs[r][c] = v;
    }
    __syncthreads();
    int d = t & 63, g = t >> 6;
    int rbase = g * 8;
    float fa[8], ca[8];
#pragma unroll
    for (int j = 0; j < 8; ++j) { fa[j] = 0.f; ca[j] = 0.f; }
    // main: k in blocks of 4, float4 LDS broadcast
    for (int k = 0; k < 160; k += 4) {
        float wf0 = Wf[(k + 0) * 64 + d], wc0 = Wc[(k + 0) * 64 + d];
        float wf1 = Wf[(k + 1) * 64 + d], wc1 = Wc[(k + 1) * 64 + d];
        float wf2 = Wf[(k + 2) * 64 + d], wc2 = Wc[(k + 2) * 64 + d];
        float wf3 = Wf[(k + 3) * 64 + d], wc3 = Wc[(k + 3) * 64 + d];
#pragma unroll
        for (int j = 0; j < 8; ++j) {
            const float4 z4 = *(const float4*)&zs[rbase + j][k];
            fa[j] += z4.x * wf0 + z4.y * wf1 + z4.z * wf2 + z4.w * wf3;
            ca[j] += z4.x * wc0 + z4.y * wc1 + z4.z * wc2 + z4.w * wc3;
        }
    }
    for (int k = 160; k < MSG_DIM; ++k) {
        float wf = Wf[k * 64 + d], wc = Wc[k * 64 + d];
#pragma unroll
        for (int j = 0; j < 8; ++j) {
            float z = zs[rbase + j][k];
            fa[j] += z * wf; ca[j] += z * wc;
        }
    }
    float bfd = bfv[d], bcd = bcv[d];
#pragma unroll
    for (int j = 0; j < 8; ++j) {
        int node = node0 + rbase + j;
        float hv = h[node * 64 + d];
        float nv = softplusf(sigmoidf(fa[j] + bfd) * softplusf(ca[j] + bcd) + hv);
        h[node * 64 + d] = nv;
        float other = __shfl_xor(nv, 1);
        if ((d & 1) == 0) hb[node * 32 + (d >> 1)] = f2_to_bf2(nv, other);
    }
}

// ---------- per-graph boundaries in sorted batch ----------
__global__ void gstart_k(const int* __restrict__ batch, int* __restrict__ gstart) {
    int g = blockIdx.x * 256 + threadIdx.x;
    if (g > N_GRAPHS) return;
    int lo = 0, hi = N_NODES;
    while (lo < hi) {
        int mid = (lo + hi) >> 1;
        if (batch[mid] < g) lo = mid + 1; else hi = mid;
    }
    gstart[g] = lo;
}

// ---------- fused pool + proj + out ----------
__global__ void poolhead_k(const float* __restrict__ h, const int* __restrict__ gstart,
                           const float* __restrict__ Wp, const float* __restrict__ bp,
                           const float* __restrict__ Wo, const float* __restrict__ bo,
                           float* __restrict__ out) {
    __shared__ float partial[4][64];
    __shared__ float pm[64];
    __shared__ float pr[128];
    int g = blockIdx.x, t = threadIdx.x;
    int s = gstart[g], e = gstart[g + 1];
    int w = t >> 6, lane = t & 63;
    float acc = 0.f;
    for (int n = s + w; n < e; n += 4) acc += h[n * 64 + lane];
    partial[w][lane] = acc;
    __syncthreads();
    if (t < 64) {
        float c = fmaxf((float)(e - s), 1.0f);
        pm[t] = (partial[0][t] + partial[1][t] + partial[2][t] + partial[3][t]) / c;
    }
    __syncthreads();
    if (t < 128) {
        float a = bp[t];
#pragma unroll 4
        for (int k = 0; k < 64; ++k) a += pm[k] * Wp[k * HOUT_DIM + t];
        pr[t] = softplusf(a) * Wo[t];
    }
    __syncthreads();
    if (t < 64) {
        float v = pr[t] + pr[t + 64];
        for (int o = 32; o > 0; o >>= 1) v += __shfl_down(v, o);
        if (t == 0) out[g] = v + bo[0];
    }
}

extern "C" void kernel_launch(void* const* d_in, const int* in_sizes, int n_in,
                              void* d_out, int out_size, void* d_ws, size_t ws_size,
                              hipStream_t stream) {
    const float* x       = (const float*)d_in[0];
    const int*   inc_n   = (const int*)d_in[1];
    const int*   inc_e   = (const int*)d_in[2];
    const float* hattr   = (const float*)d_in[3];
    const int*   batch   = (const int*)d_in[4];
    const float* W_embed = (const float*)d_in[5];
    const float* b_embed = (const float*)d_in[6];
    const float* Wf      = (const float*)d_in[7];
    const float* bf      = (const float*)d_in[8];
    const float* Wc      = (const float*)d_in[9];
    const float* bc      = (const float*)d_in[10];
    const float* W_proj  = (const float*)d_in[11];
    const float* b_proj  = (const float*)d_in[12];
    const float* W_out   = (const float*)d_in[13];
    const float* b_out   = (const float*)d_in[14];
    float* out = (float*)d_out;

    char* ws = (char*)d_ws;
    size_t off = 0;
    auto alloc = [&](size_t bytes) {
        void* p = ws + off;
        off = (off + bytes + 255) & ~(size_t)255;
        return p;
    };
    float*    h      = (float*)alloc((size_t)N_NODES * 64 * 4);
    unsigned* hb     = (unsigned*)alloc((size_t)N_NODES * 32 * 4);
    unsigned* hmean  = (unsigned*)alloc((size_t)N_HEDGES * 32 * 4);
    float*    nh     = (float*)alloc((size_t)N_NODES * 64 * 4);
    float*    na     = (float*)alloc((size_t)N_NODES * ATTR_DIM * 4);
    unsigned* hab    = (unsigned*)alloc((size_t)N_HEDGES * ATTR_PAIRS * 4);
    int*      ncnt   = (int*)alloc((size_t)N_NODES * 4);
    int*      ecnt   = (int*)alloc((size_t)N_HEDGES * 4);
    float*    nrcp   = (float*)alloc((size_t)N_NODES * 4);
    float*    ercp   = (float*)alloc((size_t)N_HEDGES * 4);
    int*      eoff   = (int*)alloc((size_t)(N_HEDGES + 1) * 4);
    int*      noff   = (int*)alloc((size_t)(N_NODES + 1) * 4);
    int*      ecur   = (int*)alloc((size_t)N_HEDGES * 4);
    int*      ncur   = (int*)alloc((size_t)N_NODES * 4);
    int*      csr_en = (int*)alloc((size_t)N_INCID * 4);
    int*      csr_ne = (int*)alloc((size_t)N_INCID * 4);
    int*      bsum   = (int*)alloc((size_t)2048 * 4);
    int*      gstart = (int*)alloc((size_t)(N_GRAPHS + 1) * 4);

    hipMemsetAsync(ncnt, 0, (size_t)N_NODES * 4, stream);
    hipMemsetAsync(ecnt, 0, (size_t)N_HEDGES * 4, stream);
    hipMemsetAsync(ecur, 0, (size_t)N_HEDGES * 4, stream);
    hipMemsetAsync(ncur, 0, (size_t)N_NODES * 4, stream);

    embed_k<<<(N_NODES + 3) / 4, 256, 0, stream>>>(x, W_embed, b_embed, h, hb);
    attrconv_k<<<(N_HEDGES * ATTR_PAIRS + 255) / 256, 256, 0, stream>>>(hattr, hab);
    count_k<<<(N_INCID + 255) / 256, 256, 0, stream>>>(inc_n, inc_e, ncnt, ecnt);
    rcp_k<<<(N_NODES + 255) / 256, 256, 0, stream>>>(ncnt, nrcp, N_NODES);
    rcp_k<<<(N_HEDGES + 255) / 256, 256, 0, stream>>>(ecnt, ercp, N_HEDGES);

    {
        int nbE = (N_HEDGES + 255) / 256;
        scan1_k<<<nbE, 256, 0, stream>>>(ecnt, eoff, bsum, N_HEDGES);
        scan2_k<<<1, 256, 0, stream>>>(bsum, nbE);
        scan3_k<<<nbE, 256, 0, stream>>>(eoff, bsum, N_HEDGES);
        int nbN = (N_NODES + 255) / 256;
        scan1_k<<<nbN, 256, 0, stream>>>(ncnt, noff, bsum, N_NODES);
        scan2_k<<<1, 256, 0, stream>>>(bsum, nbN);
        scan3_k<<<nbN, 256, 0, stream>>>(noff, bsum, N_NODES);
        sentinel_k<<<1, 64, 0, stream>>>(eoff, noff);
    }
    fill_k<<<(N_INCID + 255) / 256, 256, 0, stream>>>(inc_n, inc_e, eoff, ecur, csr_en,
                                                      noff, ncur, csr_ne);
    nodea_k<<<(N_NODES * 32 + 255) / 256, 256, 0, stream>>>(noff, csr_ne, hab, nrcp, na);

    for (int l = 0; l < N_LAYERS; ++l) {
        hmean_k<<<(N_HEDGES * 32) / 256, 256, 0, stream>>>(eoff, csr_en, hb, ercp, hmean);
        nodeh_k<<<(N_NODES * 32) / 256, 256, 0, stream>>>(noff, csr_ne, hmean, nrcp, (float2*)nh);
        layer_k<<<N_NODES / 32, 256, 0, stream>>>(Wf + (size_t)l * MSG_DIM * 64, bf + l * 64,
                                                  Wc + (size_t)l * MSG_DIM * 64, bc + l * 64,
                                                  ncnt, nh, na, h, hb);
    }
    gstart_k<<<(N_GRAPHS + 1 + 255) / 256, 256, 0, stream>>>(batch, gstart);
    poolhead_k<<<N_GRAPHS, 256, 0, stream>>>(h, gstart, W_proj, b_proj, W_out, b_out, out);
}

// Round 4
// 1332.798 us; speedup vs baseline: 3.0392x; 1.3331x over previous
//
#include <hip/hip_runtime.h>
#include <hip/hip_bf16.h>

#define N_NODES 100000
#define N_INCID 2000000
#define N_HEDGES 300000
#define IN_DIM 92
#define H_DIM 64
#define ATTR_DIM 35
#define ATTR_PAIRS 18  // padded to 36 dims
#define HOUT_DIM 128
#define N_GRAPHS 512
#define N_LAYERS 3
#define MSG_DIM 163     // 2*H_DIM + ATTR_DIM
#define ZS_STRIDE 168   // padded LDS row stride

__device__ __forceinline__ float softplusf(float x) {
    return fmaxf(x, 0.f) + log1pf(expf(-fabsf(x)));
}
__device__ __forceinline__ float sigmoidf(float x) {
    return 1.f / (1.f + expf(-x));
}
__device__ __forceinline__ float2 bf2_to_f2(unsigned v) {
    union { unsigned u; float f; } a, b;
    a.u = v << 16;
    b.u = v & 0xffff0000u;
    return make_float2(a.f, b.f);
}
__device__ __forceinline__ unsigned f2_to_bf2(float x, float y) {
    union { float f; unsigned u; } a, b;
    a.f = x; b.f = y;
    unsigned lo = (a.u + 0x7fffu + ((a.u >> 16) & 1u)) >> 16;
    unsigned hi = ((b.u + 0x7fffu + ((b.u >> 16) & 1u)) >> 16) << 16;
    return lo | hi;
}

// ---------- embed: h = x @ W_embed + b ; writes f32 h + bf16 mirror hb ----------
__global__ void embed_k(const float* __restrict__ x, const float* __restrict__ W,
                        const float* __restrict__ b, float* __restrict__ h,
                        unsigned* __restrict__ hb) {
    __shared__ float xs[4][IN_DIM];
    int node0 = blockIdx.x * 4;
    int t = threadIdx.x;
    for (int idx = t; idx < 4 * IN_DIM; idx += 256) {
        int r = idx / IN_DIM, c = idx % IN_DIM;
        int node = node0 + r;
        xs[r][c] = (node < N_NODES) ? x[node * IN_DIM + c] : 0.f;
    }
    __syncthreads();
    int r = t >> 6, d = t & 63;
    int node = node0 + r;
    if (node >= N_NODES) return;
    float acc = b[d];
#pragma unroll 4
    for (int k = 0; k < IN_DIM; ++k) acc += xs[r][k] * W[k * 64 + d];
    h[node * 64 + d] = acc;
    float other = __shfl_xor(acc, 1);
    if ((d & 1) == 0) hb[node * 32 + (d >> 1)] = f2_to_bf2(acc, other);
}

// ---------- hattr -> bf16 padded mirror ----------
__global__ void attrconv_k(const float* __restrict__ hattr, unsigned* __restrict__ hab) {
    int idx = blockIdx.x * 256 + threadIdx.x;
    if (idx >= N_HEDGES * ATTR_PAIRS) return;
    int e = idx / ATTR_PAIRS, p = idx - e * ATTR_PAIRS;
    int d0 = 2 * p, d1 = 2 * p + 1;
    float v0 = hattr[e * ATTR_DIM + d0];
    float v1 = (d1 < ATTR_DIM) ? hattr[e * ATTR_DIM + d1] : 0.f;
    hab[idx] = f2_to_bf2(v0, v1);
}

// ---------- degree counts ----------
__global__ void count_k(const int* __restrict__ inc_n, const int* __restrict__ inc_e,
                        int* __restrict__ ncnt, int* __restrict__ ecnt) {
    int i = blockIdx.x * 256 + threadIdx.x;
    if (i >= N_INCID) return;
    atomicAdd(&ncnt[inc_n[i]], 1);
    atomicAdd(&ecnt[inc_e[i]], 1);
}

__global__ void rcp_k(const int* __restrict__ cnt, float* __restrict__ rcp, int n) {
    int i = blockIdx.x * 256 + threadIdx.x;
    if (i < n) rcp[i] = 1.0f / (float)max(cnt[i], 1);
}

// ---------- exclusive scan (3-kernel) ----------
__global__ void scan1_k(const int* __restrict__ in, int* __restrict__ out,
                        int* __restrict__ bsum, int n) {
    __shared__ int tmp[256];
    int gid = blockIdx.x * 256 + threadIdx.x;
    int v = (gid < n) ? in[gid] : 0;
    tmp[threadIdx.x] = v;
    __syncthreads();
    for (int o = 1; o < 256; o <<= 1) {
        int t = (threadIdx.x >= o) ? tmp[threadIdx.x - o] : 0;
        __syncthreads();
        tmp[threadIdx.x] += t;
        __syncthreads();
    }
    if (gid < n) out[gid] = tmp[threadIdx.x] - v;
    if (threadIdx.x == 255) bsum[blockIdx.x] = tmp[255];
}

__global__ void scan2_k(int* __restrict__ bsum, int nb) {
    __shared__ int tmp[256];
    __shared__ int carry;
    if (threadIdx.x == 0) carry = 0;
    __syncthreads();
    for (int base = 0; base < nb; base += 256) {
        int gid = base + threadIdx.x;
        int v = (gid < nb) ? bsum[gid] : 0;
        tmp[threadIdx.x] = v;
        __syncthreads();
        for (int o = 1; o < 256; o <<= 1) {
            int t = (threadIdx.x >= o) ? tmp[threadIdx.x - o] : 0;
            __syncthreads();
            tmp[threadIdx.x] += t;
            __syncthreads();
        }
        if (gid < nb) bsum[gid] = tmp[threadIdx.x] - v + carry;
        __syncthreads();
        if (threadIdx.x == 0) carry += tmp[255];
        __syncthreads();
    }
}

__global__ void scan3_k(int* __restrict__ out, const int* __restrict__ bsum, int n) {
    int gid = blockIdx.x * 256 + threadIdx.x;
    if (gid < n) out[gid] += bsum[blockIdx.x];
}

__global__ void sentinel_k(int* __restrict__ eoff, int* __restrict__ noff) {
    if (threadIdx.x == 0) eoff[N_HEDGES] = N_INCID;
    if (threadIdx.x == 1) noff[N_NODES] = N_INCID;
}

// ---------- CSR fill ----------
__global__ void fill_k(const int* __restrict__ inc_n, const int* __restrict__ inc_e,
                       const int* __restrict__ eoff, int* __restrict__ ecur, int* __restrict__ csr_en,
                       const int* __restrict__ noff, int* __restrict__ ncur, int* __restrict__ csr_ne) {
    int i = blockIdx.x * 256 + threadIdx.x;
    if (i >= N_INCID) return;
    int n = inc_n[i], e = inc_e[i];
    int pe = eoff[e] + atomicAdd(&ecur[e], 1);
    csr_en[pe] = n;
    int pn = noff[n] + atomicAdd(&ncur[n], 1);
    csr_ne[pn] = e;
}

// ---------- per-hedge mean of member node bf16 rows (MLP: coalesced idx preload +
// shfl broadcast + 4 row-loads in flight) ----------
__global__ void hmean_k(const int* __restrict__ eoff, const int* __restrict__ csr_en,
                        const unsigned* __restrict__ hb, const float* __restrict__ ercp,
                        unsigned* __restrict__ hmean) {
    int idx = blockIdx.x * 256 + threadIdx.x;
    int e = idx >> 5, p = idx & 31;
    if (e >= N_HEDGES) return;
    int s = eoff[e], t = eoff[e + 1];
    float a0 = 0.f, a1 = 0.f;
    for (int base = s; base < t; base += 32) {
        int cnt = min(32, t - base);
        int myidx = (base + p < t) ? csr_en[base + p] : 0;
        for (int j = 0; j < cnt; j += 4) {
            int n0 = __shfl(myidx, j, 32);
            int n1 = __shfl(myidx, j + 1, 32);
            int n2 = __shfl(myidx, j + 2, 32);
            int n3 = __shfl(myidx, j + 3, 32);
            bool b1 = (j + 1 < cnt), b2 = (j + 2 < cnt), b3 = (j + 3 < cnt);
            unsigned v0 = hb[n0 * 32 + p];
            unsigned v1 = b1 ? hb[n1 * 32 + p] : 0u;
            unsigned v2 = b2 ? hb[n2 * 32 + p] : 0u;
            unsigned v3 = b3 ? hb[n3 * 32 + p] : 0u;
            float2 f0 = bf2_to_f2(v0), f1 = bf2_to_f2(v1);
            float2 f2 = bf2_to_f2(v2), f3 = bf2_to_f2(v3);
            a0 += (f0.x + f1.x) + (f2.x + f3.x);
            a1 += (f0.y + f1.y) + (f2.y + f3.y);
        }
    }
    float rc = ercp[e];
    hmean[e * 32 + p] = f2_to_bf2(a0 * rc, a1 * rc);
}

// ---------- per-node mean of hmean over incident hedges (same MLP pattern) ----------
__global__ void nodeh_k(const int* __restrict__ noff, const int* __restrict__ csr_ne,
                        const unsigned* __restrict__ hmean, const float* __restrict__ nrcp,
                        float2* __restrict__ nh2) {
    int idx = blockIdx.x * 256 + threadIdx.x;
    int n = idx >> 5, p = idx & 31;
    if (n >= N_NODES) return;
    int s = noff[n], t = noff[n + 1];
    float a0 = 0.f, a1 = 0.f;
    for (int base = s; base < t; base += 32) {
        int cnt = min(32, t - base);
        int myidx = (base + p < t) ? csr_ne[base + p] : 0;
        for (int j = 0; j < cnt; j += 4) {
            int e0 = __shfl(myidx, j, 32);
            int e1 = __shfl(myidx, j + 1, 32);
            int e2 = __shfl(myidx, j + 2, 32);
            int e3 = __shfl(myidx, j + 3, 32);
            bool b1 = (j + 1 < cnt), b2 = (j + 2 < cnt), b3 = (j + 3 < cnt);
            unsigned v0 = hmean[e0 * 32 + p];
            unsigned v1 = b1 ? hmean[e1 * 32 + p] : 0u;
            unsigned v2 = b2 ? hmean[e2 * 32 + p] : 0u;
            unsigned v3 = b3 ? hmean[e3 * 32 + p] : 0u;
            float2 f0 = bf2_to_f2(v0), f1 = bf2_to_f2(v1);
            float2 f2 = bf2_to_f2(v2), f3 = bf2_to_f2(v3);
            a0 += (f0.x + f1.x) + (f2.x + f3.x);
            a1 += (f0.y + f1.y) + (f2.y + f3.y);
        }
    }
    float rc = nrcp[n];
    nh2[n * 32 + p] = make_float2(a0 * rc, a1 * rc);
}

// ---------- per-node mean of hedge_attr (one-time; same MLP pattern) ----------
__global__ void nodea_k(const int* __restrict__ noff, const int* __restrict__ csr_ne,
                        const unsigned* __restrict__ hab, const float* __restrict__ nrcp,
                        float* __restrict__ na) {
    int idx = blockIdx.x * 256 + threadIdx.x;
    int n = idx >> 5, p = idx & 31;
    if (n >= N_NODES) return;
    int s = noff[n], t = noff[n + 1];
    bool act = (p < ATTR_PAIRS);
    float a0 = 0.f, a1 = 0.f;
    for (int base = s; base < t; base += 32) {
        int cnt = min(32, t - base);
        int myidx = (base + p < t) ? csr_ne[base + p] : 0;
        for (int j = 0; j < cnt; j += 4) {
            int e0 = __shfl(myidx, j, 32);
            int e1 = __shfl(myidx, j + 1, 32);
            int e2 = __shfl(myidx, j + 2, 32);
            int e3 = __shfl(myidx, j + 3, 32);
            bool b1 = (j + 1 < cnt), b2 = (j + 2 < cnt), b3 = (j + 3 < cnt);
            unsigned v0 = act ? hab[e0 * ATTR_PAIRS + p] : 0u;
            unsigned v1 = (act && b1) ? hab[e1 * ATTR_PAIRS + p] : 0u;
            unsigned v2 = (act && b2) ? hab[e2 * ATTR_PAIRS + p] : 0u;
            unsigned v3 = (act && b3) ? hab[e3 * ATTR_PAIRS + p] : 0u;
            float2 f0 = bf2_to_f2(v0), f1 = bf2_to_f2(v1);
            float2 f2 = bf2_to_f2(v2), f3 = bf2_to_f2(v3);
            a0 += (f0.x + f1.x) + (f2.x + f3.x);
            a1 += (f0.y + f1.y) + (f2.y + f3.y);
        }
    }
    if (!act) return;
    float rc = nrcp[n];
    int d0 = 2 * p;
    na[n * ATTR_DIM + d0] = a0 * rc;
    if (d0 + 1 < ATTR_DIM) na[n * ATTR_DIM + d0 + 1] = a1 * rc;
}

// ---------- fused gate/core GEMV + activation; 32 nodes/block, 8 nodes/wave ----------
__global__ void layer_k(const float* __restrict__ Wf, const float* __restrict__ bfv,
                        const float* __restrict__ Wc, const float* __restrict__ bcv,
                        const int* __restrict__ ncnt, const float* __restrict__ nh,
                        const float* __restrict__ na, float* __restrict__ h,
                        unsigned* __restrict__ hb) {
    __shared__ float zs[32][ZS_STRIDE];
    int node0 = blockIdx.x * 32;  // N_NODES % 32 == 0
    int t = threadIdx.x;
    for (int idx = t; idx < 32 * MSG_DIM; idx += 256) {
        int r = idx / MSG_DIM, c = idx - r * MSG_DIM;
        int node = node0 + r;
        float v;
        if (c < 64)       v = (ncnt[node] > 0) ? h[node * 64 + c] : 0.f;
        else if (c < 128) v = nh[node * 64 + (c - 64)];
        else              v = na[node * ATTR_DIM + (c - 128)];
        zs[r][c] = v;
    }
    __syncthreads();
    int d = t & 63, g = t >> 6;
    int rbase = g * 8;
    float fa[8], ca[8];
#pragma unroll
    for (int j = 0; j < 8; ++j) { fa[j] = 0.f; ca[j] = 0.f; }
    for (int k = 0; k < 160; k += 4) {
        float wf0 = Wf[(k + 0) * 64 + d], wc0 = Wc[(k + 0) * 64 + d];
        float wf1 = Wf[(k + 1) * 64 + d], wc1 = Wc[(k + 1) * 64 + d];
        float wf2 = Wf[(k + 2) * 64 + d], wc2 = Wc[(k + 2) * 64 + d];
        float wf3 = Wf[(k + 3) * 64 + d], wc3 = Wc[(k + 3) * 64 + d];
#pragma unroll
        for (int j = 0; j < 8; ++j) {
            const float4 z4 = *(const float4*)&zs[rbase + j][k];
            fa[j] += z4.x * wf0 + z4.y * wf1 + z4.z * wf2 + z4.w * wf3;
            ca[j] += z4.x * wc0 + z4.y * wc1 + z4.z * wc2 + z4.w * wc3;
        }
    }
    for (int k = 160; k < MSG_DIM; ++k) {
        float wf = Wf[k * 64 + d], wc = Wc[k * 64 + d];
#pragma unroll
        for (int j = 0; j < 8; ++j) {
            float z = zs[rbase + j][k];
            fa[j] += z * wf; ca[j] += z * wc;
        }
    }
    float bfd = bfv[d], bcd = bcv[d];
#pragma unroll
    for (int j = 0; j < 8; ++j) {
        int node = node0 + rbase + j;
        float hv = h[node * 64 + d];
        float nv = softplusf(sigmoidf(fa[j] + bfd) * softplusf(ca[j] + bcd) + hv);
        h[node * 64 + d] = nv;
        float other = __shfl_xor(nv, 1);
        if ((d & 1) == 0) hb[node * 32 + (d >> 1)] = f2_to_bf2(nv, other);
    }
}

// ---------- per-graph boundaries in sorted batch ----------
__global__ void gstart_k(const int* __restrict__ batch, int* __restrict__ gstart) {
    int g = blockIdx.x * 256 + threadIdx.x;
    if (g > N_GRAPHS) return;
    int lo = 0, hi = N_NODES;
    while (lo < hi) {
        int mid = (lo + hi) >> 1;
        if (batch[mid] < g) lo = mid + 1; else hi = mid;
    }
    gstart[g] = lo;
}

// ---------- fused pool + proj + out ----------
__global__ void poolhead_k(const float* __restrict__ h, const int* __restrict__ gstart,
                           const float* __restrict__ Wp, const float* __restrict__ bp,
                           const float* __restrict__ Wo, const float* __restrict__ bo,
                           float* __restrict__ out) {
    __shared__ float partial[4][64];
    __shared__ float pm[64];
    __shared__ float pr[128];
    int g = blockIdx.x, t = threadIdx.x;
    int s = gstart[g], e = gstart[g + 1];
    int w = t >> 6, lane = t & 63;
    float acc = 0.f;
    for (int n = s + w; n < e; n += 4) acc += h[n * 64 + lane];
    partial[w][lane] = acc;
    __syncthreads();
    if (t < 64) {
        float c = fmaxf((float)(e - s), 1.0f);
        pm[t] = (partial[0][t] + partial[1][t] + partial[2][t] + partial[3][t]) / c;
    }
    __syncthreads();
    if (t < 128) {
        float a = bp[t];
#pragma unroll 4
        for (int k = 0; k < 64; ++k) a += pm[k] * Wp[k * HOUT_DIM + t];
        pr[t] = softplusf(a) * Wo[t];
    }
    __syncthreads();
    if (t < 64) {
        float v = pr[t] + pr[t + 64];
        for (int o = 32; o > 0; o >>= 1) v += __shfl_down(v, o);
        if (t == 0) out[g] = v + bo[0];
    }
}

extern "C" void kernel_launch(void* const* d_in, const int* in_sizes, int n_in,
                              void* d_out, int out_size, void* d_ws, size_t ws_size,
                              hipStream_t stream) {
    const float* x       = (const float*)d_in[0];
    const int*   inc_n   = (const int*)d_in[1];
    const int*   inc_e   = (const int*)d_in[2];
    const float* hattr   = (const float*)d_in[3];
    const int*   batch   = (const int*)d_in[4];
    const float* W_embed = (const float*)d_in[5];
    const float* b_embed = (const float*)d_in[6];
    const float* Wf      = (const float*)d_in[7];
    const float* bf      = (const float*)d_in[8];
    const float* Wc      = (const float*)d_in[9];
    const float* bc      = (const float*)d_in[10];
    const float* W_proj  = (const float*)d_in[11];
    const float* b_proj  = (const float*)d_in[12];
    const float* W_out   = (const float*)d_in[13];
    const float* b_out   = (const float*)d_in[14];
    float* out = (float*)d_out;

    char* ws = (char*)d_ws;
    size_t off = 0;
    auto alloc = [&](size_t bytes) {
        void* p = ws + off;
        off = (off + bytes + 255) & ~(size_t)255;
        return p;
    };
    float*    h      = (float*)alloc((size_t)N_NODES * 64 * 4);
    unsigned* hb     = (unsigned*)alloc((size_t)N_NODES * 32 * 4);
    unsigned* hmean  = (unsigned*)alloc((size_t)N_HEDGES * 32 * 4);
    float*    nh     = (float*)alloc((size_t)N_NODES * 64 * 4);
    float*    na     = (float*)alloc((size_t)N_NODES * ATTR_DIM * 4);
    unsigned* hab    = (unsigned*)alloc((size_t)N_HEDGES * ATTR_PAIRS * 4);
    int*      ncnt   = (int*)alloc((size_t)N_NODES * 4);
    int*      ecnt   = (int*)alloc((size_t)N_HEDGES * 4);
    float*    nrcp   = (float*)alloc((size_t)N_NODES * 4);
    float*    ercp   = (float*)alloc((size_t)N_HEDGES * 4);
    int*      eoff   = (int*)alloc((size_t)(N_HEDGES + 1) * 4);
    int*      noff   = (int*)alloc((size_t)(N_NODES + 1) * 4);
    int*      ecur   = (int*)alloc((size_t)N_HEDGES * 4);
    int*      ncur   = (int*)alloc((size_t)N_NODES * 4);
    int*      csr_en = (int*)alloc((size_t)N_INCID * 4);
    int*      csr_ne = (int*)alloc((size_t)N_INCID * 4);
    int*      bsum   = (int*)alloc((size_t)2048 * 4);
    int*      gstart = (int*)alloc((size_t)(N_GRAPHS + 1) * 4);

    hipMemsetAsync(ncnt, 0, (size_t)N_NODES * 4, stream);
    hipMemsetAsync(ecnt, 0, (size_t)N_HEDGES * 4, stream);
    hipMemsetAsync(ecur, 0, (size_t)N_HEDGES * 4, stream);
    hipMemsetAsync(ncur, 0, (size_t)N_NODES * 4, stream);

    embed_k<<<(N_NODES + 3) / 4, 256, 0, stream>>>(x, W_embed, b_embed, h, hb);
    attrconv_k<<<(N_HEDGES * ATTR_PAIRS + 255) / 256, 256, 0, stream>>>(hattr, hab);
    count_k<<<(N_INCID + 255) / 256, 256, 0, stream>>>(inc_n, inc_e, ncnt, ecnt);
    rcp_k<<<(N_NODES + 255) / 256, 256, 0, stream>>>(ncnt, nrcp, N_NODES);
    rcp_k<<<(N_HEDGES + 255) / 256, 256, 0, stream>>>(ecnt, ercp, N_HEDGES);

    {
        int nbE = (N_HEDGES + 255) / 256;
        scan1_k<<<nbE, 256, 0, stream>>>(ecnt, eoff, bsum, N_HEDGES);
        scan2_k<<<1, 256, 0, stream>>>(bsum, nbE);
        scan3_k<<<nbE, 256, 0, stream>>>(eoff, bsum, N_HEDGES);
        int nbN = (N_NODES + 255) / 256;
        scan1_k<<<nbN, 256, 0, stream>>>(ncnt, noff, bsum, N_NODES);
        scan2_k<<<1, 256, 0, stream>>>(bsum, nbN);
        scan3_k<<<nbN, 256, 0, stream>>>(noff, bsum, N_NODES);
        sentinel_k<<<1, 64, 0, stream>>>(eoff, noff);
    }
    fill_k<<<(N_INCID + 255) / 256, 256, 0, stream>>>(inc_n, inc_e, eoff, ecur, csr_en,
                                                      noff, ncur, csr_ne);
    nodea_k<<<(N_NODES * 32) / 256, 256, 0, stream>>>(noff, csr_ne, hab, nrcp, na);

    for (int l = 0; l < N_LAYERS; ++l) {
        hmean_k<<<(N_HEDGES * 32) / 256, 256, 0, stream>>>(eoff, csr_en, hb, ercp, hmean);
        nodeh_k<<<(N_NODES * 32) / 256, 256, 0, stream>>>(noff, csr_ne, hmean, nrcp, (float2*)nh);
        layer_k<<<N_NODES / 32, 256, 0, stream>>>(Wf + (size_t)l * MSG_DIM * 64, bf + l * 64,
                                                  Wc + (size_t)l * MSG_DIM * 64, bc + l * 64,
                                                  ncnt, nh, na, h, hb);
    }
    gstart_k<<<(N_GRAPHS + 1 + 255) / 256, 256, 0, stream>>>(batch, gstart);
    poolhead_k<<<N_GRAPHS, 256, 0, stream>>>(h, gstart, W_proj, b_proj, W_out, b_out, out);
}

// Round 5
// 1035.688 us; speedup vs baseline: 3.9111x; 1.2869x over previous
//
#include <hip/hip_runtime.h>
#include <hip/hip_bf16.h>

#define N_NODES 100000
#define N_INCID 2000000
#define N_HEDGES 300000
#define IN_DIM 92
#define H_DIM 64
#define ATTR_DIM 35
#define ATTR_PAIRS 18
#define HOUT_DIM 128
#define N_GRAPHS 512
#define N_LAYERS 3
#define MSG_DIM 163
#define ZS_STRIDE 168

// sort geometry
#define IPB 8192                 // items per block for hist/scatter
#define NBLK 245                 // ceil(2e6 / 8192)
#define ESHIFT 9
#define NB_E 586                 // ceil(300000/512)
#define NSHIFT 8
#define NB_N 391                 // ceil(100000/256)

__device__ __forceinline__ float softplusf(float x) {
    return fmaxf(x, 0.f) + log1pf(expf(-fabsf(x)));
}
__device__ __forceinline__ float sigmoidf(float x) {
    return 1.f / (1.f + expf(-x));
}
__device__ __forceinline__ float2 bf2_to_f2(unsigned v) {
    union { unsigned u; float f; } a, b;
    a.u = v << 16;
    b.u = v & 0xffff0000u;
    return make_float2(a.f, b.f);
}
__device__ __forceinline__ unsigned f2_to_bf2(float x, float y) {
    union { float f; unsigned u; } a, b;
    a.f = x; b.f = y;
    unsigned lo = (a.u + 0x7fffu + ((a.u >> 16) & 1u)) >> 16;
    unsigned hi = ((b.u + 0x7fffu + ((b.u >> 16) & 1u)) >> 16) << 16;
    return lo | hi;
}

// ---------- embed ----------
__global__ void embed_k(const float* __restrict__ x, const float* __restrict__ W,
                        const float* __restrict__ b, float* __restrict__ h,
                        unsigned* __restrict__ hb) {
    __shared__ float xs[4][IN_DIM];
    int node0 = blockIdx.x * 4;
    int t = threadIdx.x;
    for (int idx = t; idx < 4 * IN_DIM; idx += 256) {
        int r = idx / IN_DIM, c = idx % IN_DIM;
        int node = node0 + r;
        xs[r][c] = (node < N_NODES) ? x[node * IN_DIM + c] : 0.f;
    }
    __syncthreads();
    int r = t >> 6, d = t & 63;
    int node = node0 + r;
    if (node >= N_NODES) return;
    float acc = b[d];
#pragma unroll 4
    for (int k = 0; k < IN_DIM; ++k) acc += xs[r][k] * W[k * 64 + d];
    h[node * 64 + d] = acc;
    float other = __shfl_xor(acc, 1);
    if ((d & 1) == 0) hb[node * 32 + (d >> 1)] = f2_to_bf2(acc, other);
}

// ---------- hattr -> bf16 padded mirror ----------
__global__ void attrconv_k(const float* __restrict__ hattr, unsigned* __restrict__ hab) {
    int idx = blockIdx.x * 256 + threadIdx.x;
    if (idx >= N_HEDGES * ATTR_PAIRS) return;
    int e = idx / ATTR_PAIRS, p = idx - e * ATTR_PAIRS;
    int d0 = 2 * p, d1 = 2 * p + 1;
    float v0 = hattr[e * ATTR_DIM + d0];
    float v1 = (d1 < ATTR_DIM) ? hattr[e * ATTR_DIM + d1] : 0.f;
    hab[idx] = f2_to_bf2(v0, v1);
}

// ---------- sort S1: per-block bucket histogram ----------
__global__ void sorthist_k(const int* __restrict__ key, int* __restrict__ hist,
                           int kshift, int NB) {
    __shared__ int cnt[640];
    int blk = blockIdx.x;
    for (int i = threadIdx.x; i < NB; i += 256) cnt[i] = 0;
    __syncthreads();
    int base = blk * IPB;
    int end = min(base + IPB, N_INCID);
    for (int i = base + threadIdx.x; i < end; i += 256)
        atomicAdd(&cnt[key[i] >> kshift], 1);
    __syncthreads();
    for (int i = threadIdx.x; i < NB; i += 256) hist[blk * NB + i] = cnt[i];
}

// ---------- scan with bucket-major remap: logical gid = bucket*NBLK + blk ----------
__global__ void scanR1_k(const int* __restrict__ in, int* __restrict__ out,
                         int* __restrict__ bsum, int n, int NB) {
    __shared__ int tmp[256];
    int gid = blockIdx.x * 256 + threadIdx.x;
    int v = 0;
    if (gid < n) {
        int bucket = gid / NBLK, blk = gid - bucket * NBLK;
        v = in[blk * NB + bucket];
    }
    tmp[threadIdx.x] = v;
    __syncthreads();
    for (int o = 1; o < 256; o <<= 1) {
        int t = (threadIdx.x >= o) ? tmp[threadIdx.x - o] : 0;
        __syncthreads();
        tmp[threadIdx.x] += t;
        __syncthreads();
    }
    if (gid < n) out[gid] = tmp[threadIdx.x] - v;
    if (threadIdx.x == 255) bsum[blockIdx.x] = tmp[255];
}

__global__ void scan2_k(int* __restrict__ bsum, int nb) {
    __shared__ int tmp[256];
    __shared__ int carry;
    if (threadIdx.x == 0) carry = 0;
    __syncthreads();
    for (int base = 0; base < nb; base += 256) {
        int gid = base + threadIdx.x;
        int v = (gid < nb) ? bsum[gid] : 0;
        tmp[threadIdx.x] = v;
        __syncthreads();
        for (int o = 1; o < 256; o <<= 1) {
            int t = (threadIdx.x >= o) ? tmp[threadIdx.x - o] : 0;
            __syncthreads();
            tmp[threadIdx.x] += t;
            __syncthreads();
        }
        if (gid < nb) bsum[gid] = tmp[threadIdx.x] - v + carry;
        __syncthreads();
        if (threadIdx.x == 0) carry += tmp[255];
        __syncthreads();
    }
}

__global__ void scan3_k(int* __restrict__ out, const int* __restrict__ bsum, int n) {
    int gid = blockIdx.x * 256 + threadIdx.x;
    if (gid < n) out[gid] += bsum[blockIdx.x];
}

// ---------- sort S3: scatter into bucketed staging (block-local contiguous runs) ----------
__global__ void sortscat_k(const int* __restrict__ key, const int* __restrict__ val,
                           const int* __restrict__ soff, uint2* __restrict__ stage,
                           int kshift, int NB) {
    __shared__ int cur[640], bas[640];
    int blk = blockIdx.x;
    for (int i = threadIdx.x; i < NB; i += 256) {
        cur[i] = 0;
        bas[i] = soff[i * NBLK + blk];
    }
    __syncthreads();
    int base = blk * IPB;
    int end = min(base + IPB, N_INCID);
    for (int i = base + threadIdx.x; i < end; i += 256) {
        int k = key[i], b = k >> kshift;
        int d = bas[b] + atomicAdd(&cur[b], 1);
        stage[d] = make_uint2((unsigned)k, (unsigned)val[i]);
    }
}

// ---------- sort S4: fine counting-sort within bucket; emits csr + offsets + rcp + cnt ----------
__global__ void sortfine_k(const uint2* __restrict__ stage, const int* __restrict__ soff,
                           int* __restrict__ csr, int* __restrict__ koff,
                           float* __restrict__ krcp, int* __restrict__ kcnt,
                           int kshift, int NB, int NKEYS, int nlog) {
    __shared__ int cnt[512], off[512], cur[512];
    int b = blockIdx.x;
    int KPB = 1 << kshift;
    int kbase = b << kshift;
    int base = soff[b * NBLK];
    int end = (b == NB - 1) ? N_INCID : soff[(b + 1) * NBLK];
    for (int i = threadIdx.x; i < KPB; i += 256) cnt[i] = 0;
    __syncthreads();
    for (int i = base + threadIdx.x; i < end; i += 256)
        atomicAdd(&cnt[(int)stage[i].x - kbase], 1);
    __syncthreads();
    if (threadIdx.x == 0) {
        int run = 0;
        for (int k = 0; k < KPB; ++k) { off[k] = run; run += cnt[k]; }
    }
    __syncthreads();
    for (int k = threadIdx.x; k < KPB; k += 256) {
        int gk = kbase + k;
        if (gk < NKEYS) {
            koff[gk] = base + off[k];
            krcp[gk] = 1.0f / (float)max(cnt[k], 1);
            kcnt[gk] = cnt[k];
        }
        cur[k] = 0;
    }
    __syncthreads();
    for (int i = base + threadIdx.x; i < end; i += 256) {
        uint2 it = stage[i];
        int lk = (int)it.x - kbase;
        int pos = base + off[lk] + atomicAdd(&cur[lk], 1);
        csr[pos] = (int)it.y;
    }
}

__global__ void sentinel_k(int* __restrict__ eoff, int* __restrict__ noff) {
    if (threadIdx.x == 0) eoff[N_HEDGES] = N_INCID;
    if (threadIdx.x == 1) noff[N_NODES] = N_INCID;
}

// ---------- per-hedge mean of member node bf16 rows (8-deep MLP) ----------
__global__ void hmean_k(const int* __restrict__ eoff, const int* __restrict__ csr_en,
                        const unsigned* __restrict__ hb, const float* __restrict__ ercp,
                        unsigned* __restrict__ hmean) {
    int idx = blockIdx.x * 256 + threadIdx.x;
    int e = idx >> 5, p = idx & 31;
    if (e >= N_HEDGES) return;
    int s = eoff[e], t = eoff[e + 1];
    float a0 = 0.f, a1 = 0.f;
    for (int base = s; base < t; base += 32) {
        int cnt = min(32, t - base);
        int myidx = (base + p < t) ? csr_en[base + p] : 0;
        for (int j = 0; j < cnt; j += 8) {
            unsigned v[8];
#pragma unroll
            for (int q = 0; q < 8; ++q) {
                int nq = __shfl(myidx, j + q, 32);
                v[q] = (j + q < cnt) ? hb[nq * 32 + p] : 0u;
            }
#pragma unroll
            for (int q = 0; q < 8; ++q) {
                float2 f = bf2_to_f2(v[q]);
                a0 += f.x; a1 += f.y;
            }
        }
    }
    float rc = ercp[e];
    hmean[e * 32 + p] = f2_to_bf2(a0 * rc, a1 * rc);
}

// ---------- per-node mean of hmean (8-deep MLP) ----------
__global__ void nodeh_k(const int* __restrict__ noff, const int* __restrict__ csr_ne,
                        const unsigned* __restrict__ hmean, const float* __restrict__ nrcp,
                        float2* __restrict__ nh2) {
    int idx = blockIdx.x * 256 + threadIdx.x;
    int n = idx >> 5, p = idx & 31;
    if (n >= N_NODES) return;
    int s = noff[n], t = noff[n + 1];
    float a0 = 0.f, a1 = 0.f;
    for (int base = s; base < t; base += 32) {
        int cnt = min(32, t - base);
        int myidx = (base + p < t) ? csr_ne[base + p] : 0;
        for (int j = 0; j < cnt; j += 8) {
            unsigned v[8];
#pragma unroll
            for (int q = 0; q < 8; ++q) {
                int eq = __shfl(myidx, j + q, 32);
                v[q] = (j + q < cnt) ? hmean[eq * 32 + p] : 0u;
            }
#pragma unroll
            for (int q = 0; q < 8; ++q) {
                float2 f = bf2_to_f2(v[q]);
                a0 += f.x; a1 += f.y;
            }
        }
    }
    float rc = nrcp[n];
    nh2[n * 32 + p] = make_float2(a0 * rc, a1 * rc);
}

// ---------- per-node mean of hedge_attr (one-time; 8-deep MLP) ----------
__global__ void nodea_k(const int* __restrict__ noff, const int* __restrict__ csr_ne,
                        const unsigned* __restrict__ hab, const float* __restrict__ nrcp,
                        float* __restrict__ na) {
    int idx = blockIdx.x * 256 + threadIdx.x;
    int n = idx >> 5, p = idx & 31;
    if (n >= N_NODES) return;
    int s = noff[n], t = noff[n + 1];
    bool act = (p < ATTR_PAIRS);
    float a0 = 0.f, a1 = 0.f;
    for (int base = s; base < t; base += 32) {
        int cnt = min(32, t - base);
        int myidx = (base + p < t) ? csr_ne[base + p] : 0;
        for (int j = 0; j < cnt; j += 8) {
            unsigned v[8];
#pragma unroll
            for (int q = 0; q < 8; ++q) {
                int eq = __shfl(myidx, j + q, 32);
                v[q] = (act && (j + q < cnt)) ? hab[eq * ATTR_PAIRS + p] : 0u;
            }
#pragma unroll
            for (int q = 0; q < 8; ++q) {
                float2 f = bf2_to_f2(v[q]);
                a0 += f.x; a1 += f.y;
            }
        }
    }
    if (!act) return;
    float rc = nrcp[n];
    int d0 = 2 * p;
    na[n * ATTR_DIM + d0] = a0 * rc;
    if (d0 + 1 < ATTR_DIM) na[n * ATTR_DIM + d0 + 1] = a1 * rc;
}

// ---------- fused gate/core GEMV + activation ----------
__global__ void layer_k(const float* __restrict__ Wf, const float* __restrict__ bfv,
                        const float* __restrict__ Wc, const float* __restrict__ bcv,
                        const int* __restrict__ ncnt, const float* __restrict__ nh,
                        const float* __restrict__ na, float* __restrict__ h,
                        unsigned* __restrict__ hb) {
    __shared__ float zs[32][ZS_STRIDE];
    int node0 = blockIdx.x * 32;
    int t = threadIdx.x;
    for (int idx = t; idx < 32 * MSG_DIM; idx += 256) {
        int r = idx / MSG_DIM, c = idx - r * MSG_DIM;
        int node = node0 + r;
        float v;
        if (c < 64)       v = (ncnt[node] > 0) ? h[node * 64 + c] : 0.f;
        else if (c < 128) v = nh[node * 64 + (c - 64)];
        else              v = na[node * ATTR_DIM + (c - 128)];
        zs[r][c] = v;
    }
    __syncthreads();
    int d = t & 63, g = t >> 6;
    int rbase = g * 8;
    float fa[8], ca[8];
#pragma unroll
    for (int j = 0; j < 8; ++j) { fa[j] = 0.f; ca[j] = 0.f; }
    for (int k = 0; k < 160; k += 4) {
        float wf0 = Wf[(k + 0) * 64 + d], wc0 = Wc[(k + 0) * 64 + d];
        float wf1 = Wf[(k + 1) * 64 + d], wc1 = Wc[(k + 1) * 64 + d];
        float wf2 = Wf[(k + 2) * 64 + d], wc2 = Wc[(k + 2) * 64 + d];
        float wf3 = Wf[(k + 3) * 64 + d], wc3 = Wc[(k + 3) * 64 + d];
#pragma unroll
        for (int j = 0; j < 8; ++j) {
            const float4 z4 = *(const float4*)&zs[rbase + j][k];
            fa[j] += z4.x * wf0 + z4.y * wf1 + z4.z * wf2 + z4.w * wf3;
            ca[j] += z4.x * wc0 + z4.y * wc1 + z4.z * wc2 + z4.w * wc3;
        }
    }
    for (int k = 160; k < MSG_DIM; ++k) {
        float wf = Wf[k * 64 + d], wc = Wc[k * 64 + d];
#pragma unroll
        for (int j = 0; j < 8; ++j) {
            float z = zs[rbase + j][k];
            fa[j] += z * wf; ca[j] += z * wc;
        }
    }
    float bfd = bfv[d], bcd = bcv[d];
#pragma unroll
    for (int j = 0; j < 8; ++j) {
        int node = node0 + rbase + j;
        float hv = h[node * 64 + d];
        float nv = softplusf(sigmoidf(fa[j] + bfd) * softplusf(ca[j] + bcd) + hv);
        h[node * 64 + d] = nv;
        float other = __shfl_xor(nv, 1);
        if ((d & 1) == 0) hb[node * 32 + (d >> 1)] = f2_to_bf2(nv, other);
    }
}

// ---------- per-graph boundaries ----------
__global__ void gstart_k(const int* __restrict__ batch, int* __restrict__ gstart) {
    int g = blockIdx.x * 256 + threadIdx.x;
    if (g > N_GRAPHS) return;
    int lo = 0, hi = N_NODES;
    while (lo < hi) {
        int mid = (lo + hi) >> 1;
        if (batch[mid] < g) lo = mid + 1; else hi = mid;
    }
    gstart[g] = lo;
}

// ---------- fused pool + proj + out ----------
__global__ void poolhead_k(const float* __restrict__ h, const int* __restrict__ gstart,
                           const float* __restrict__ Wp, const float* __restrict__ bp,
                           const float* __restrict__ Wo, const float* __restrict__ bo,
                           float* __restrict__ out) {
    __shared__ float partial[4][64];
    __shared__ float pm[64];
    __shared__ float pr[128];
    int g = blockIdx.x, t = threadIdx.x;
    int s = gstart[g], e = gstart[g + 1];
    int w = t >> 6, lane = t & 63;
    float acc = 0.f;
    for (int n = s + w; n < e; n += 4) acc += h[n * 64 + lane];
    partial[w][lane] = acc;
    __syncthreads();
    if (t < 64) {
        float c = fmaxf((float)(e - s), 1.0f);
        pm[t] = (partial[0][t] + partial[1][t] + partial[2][t] + partial[3][t]) / c;
    }
    __syncthreads();
    if (t < 128) {
        float a = bp[t];
#pragma unroll 4
        for (int k = 0; k < 64; ++k) a += pm[k] * Wp[k * HOUT_DIM + t];
        pr[t] = softplusf(a) * Wo[t];
    }
    __syncthreads();
    if (t < 64) {
        float v = pr[t] + pr[t + 64];
        for (int o = 32; o > 0; o >>= 1) v += __shfl_down(v, o);
        if (t == 0) out[g] = v + bo[0];
    }
}

extern "C" void kernel_launch(void* const* d_in, const int* in_sizes, int n_in,
                              void* d_out, int out_size, void* d_ws, size_t ws_size,
                              hipStream_t stream) {
    const float* x       = (const float*)d_in[0];
    const int*   inc_n   = (const int*)d_in[1];
    const int*   inc_e   = (const int*)d_in[2];
    const float* hattr   = (const float*)d_in[3];
    const int*   batch   = (const int*)d_in[4];
    const float* W_embed = (const float*)d_in[5];
    const float* b_embed = (const float*)d_in[6];
    const float* Wf      = (const float*)d_in[7];
    const float* bf      = (const float*)d_in[8];
    const float* Wc      = (const float*)d_in[9];
    const float* bc      = (const float*)d_in[10];
    const float* W_proj  = (const float*)d_in[11];
    const float* b_proj  = (const float*)d_in[12];
    const float* W_out   = (const float*)d_in[13];
    const float* b_out   = (const float*)d_in[14];
    float* out = (float*)d_out;

    char* ws = (char*)d_ws;
    size_t off = 0;
    auto alloc = [&](size_t bytes) {
        void* p = ws + off;
        off = (off + bytes + 255) & ~(size_t)255;
        return p;
    };
    float*    h      = (float*)alloc((size_t)N_NODES * 64 * 4);
    unsigned* hb     = (unsigned*)alloc((size_t)N_NODES * 32 * 4);
    unsigned* hmean  = (unsigned*)alloc((size_t)N_HEDGES * 32 * 4);  // also sort staging (16MB < 38.4MB)
    float*    nh     = (float*)alloc((size_t)N_NODES * 64 * 4);
    float*    na     = (float*)alloc((size_t)N_NODES * ATTR_DIM * 4);
    unsigned* hab    = (unsigned*)alloc((size_t)N_HEDGES * ATTR_PAIRS * 4);
    int*      ncnt   = (int*)alloc((size_t)N_NODES * 4);
    int*      ecnt   = (int*)alloc((size_t)N_HEDGES * 4);
    float*    nrcp   = (float*)alloc((size_t)N_NODES * 4);
    float*    ercp   = (float*)alloc((size_t)N_HEDGES * 4);
    int*      eoff   = (int*)alloc((size_t)(N_HEDGES + 1) * 4);
    int*      noff   = (int*)alloc((size_t)(N_NODES + 1) * 4);
    int*      csr_en = (int*)alloc((size_t)N_INCID * 4);
    int*      csr_ne = (int*)alloc((size_t)N_INCID * 4);
    int*      hist   = (int*)alloc((size_t)NB_E * NBLK * 4);   // max of both sides
    int*      soff   = (int*)alloc((size_t)NB_E * NBLK * 4);
    int*      bsum   = (int*)alloc((size_t)2048 * 4);
    int*      gstart = (int*)alloc((size_t)(N_GRAPHS + 1) * 4);
    uint2*    stage  = (uint2*)hmean;

    embed_k<<<(N_NODES + 3) / 4, 256, 0, stream>>>(x, W_embed, b_embed, h, hb);
    attrconv_k<<<(N_HEDGES * ATTR_PAIRS + 255) / 256, 256, 0, stream>>>(hattr, hab);

    // ---- hedge-side sort: key=inc_e, val=inc_n -> csr_en, eoff, ercp ----
    {
        int nlog = NB_E * NBLK;                     // 143570
        int nsb = (nlog + 255) / 256;               // 561
        sorthist_k<<<NBLK, 256, 0, stream>>>(inc_e, hist, ESHIFT, NB_E);
        scanR1_k<<<nsb, 256, 0, stream>>>(hist, soff, bsum, nlog, NB_E);
        scan2_k<<<1, 256, 0, stream>>>(bsum, nsb);
        scan3_k<<<nsb, 256, 0, stream>>>(soff, bsum, nlog);
        sortscat_k<<<NBLK, 256, 0, stream>>>(inc_e, inc_n, soff, stage, ESHIFT, NB_E);
        sortfine_k<<<NB_E, 256, 0, stream>>>(stage, soff, csr_en, eoff, ercp, ecnt,
                                             ESHIFT, NB_E, N_HEDGES, nlog);
    }
    // ---- node-side sort: key=inc_n, val=inc_e -> csr_ne, noff, nrcp, ncnt ----
    {
        int nlog = NB_N * NBLK;                     // 95795
        int nsb = (nlog + 255) / 256;               // 375
        sorthist_k<<<NBLK, 256, 0, stream>>>(inc_n, hist, NSHIFT, NB_N);
        scanR1_k<<<nsb, 256, 0, stream>>>(hist, soff, bsum, nlog, NB_N);
        scan2_k<<<1, 256, 0, stream>>>(bsum, nsb);
        scan3_k<<<nsb, 256, 0, stream>>>(soff, bsum, nlog);
        sortscat_k<<<NBLK, 256, 0, stream>>>(inc_n, inc_e, soff, stage, NSHIFT, NB_N);
        sortfine_k<<<NB_N, 256, 0, stream>>>(stage, soff, csr_ne, noff, nrcp, ncnt,
                                             NSHIFT, NB_N, N_NODES, nlog);
    }
    sentinel_k<<<1, 64, 0, stream>>>(eoff, noff);

    nodea_k<<<(N_NODES * 32) / 256, 256, 0, stream>>>(noff, csr_ne, hab, nrcp, na);

    for (int l = 0; l < N_LAYERS; ++l) {
        hmean_k<<<(N_HEDGES * 32) / 256, 256, 0, stream>>>(eoff, csr_en, hb, ercp, hmean);
        nodeh_k<<<(N_NODES * 32) / 256, 256, 0, stream>>>(noff, csr_ne, hmean, nrcp, (float2*)nh);
        layer_k<<<N_NODES / 32, 256, 0, stream>>>(Wf + (size_t)l * MSG_DIM * 64, bf + l * 64,
                                                  Wc + (size_t)l * MSG_DIM * 64, bc + l * 64,
                                                  ncnt, nh, na, h, hb);
    }
    gstart_k<<<(N_GRAPHS + 1 + 255) / 256, 256, 0, stream>>>(batch, gstart);
    poolhead_k<<<N_GRAPHS, 256, 0, stream>>>(h, gstart, W_proj, b_proj, W_out, b_out, out);
}

// Round 6
// 814.548 us; speedup vs baseline: 4.9729x; 1.2715x over previous
//
#include <hip/hip_runtime.h>
#include <hip/hip_bf16.h>

#define N_NODES 100000
#define N_INCID 2000000
#define N_HEDGES 300000
#define IN_DIM 92
#define H_DIM 64
#define ATTR_DIM 35
#define ATTR_PAIRS 18
#define HOUT_DIM 128
#define N_GRAPHS 512
#define N_LAYERS 3
#define MSG_DIM 163
#define KPAIRS 96        // K padded to 192 bf16 = 96 uint pairs
#define ZLDS 100         // LDS row stride in uints (400B, breaks pow2 banking)

// sort geometry
#define IPB 8192
#define NBLK 245
#define ESHIFT 9
#define NB_E 586
#define NSHIFT 8
#define NB_N 391

typedef short bf16x8 __attribute__((ext_vector_type(8)));
typedef float f32x4 __attribute__((ext_vector_type(4)));

__device__ __forceinline__ float softplusf(float x) {
    return fmaxf(x, 0.f) + log1pf(expf(-fabsf(x)));
}
__device__ __forceinline__ float sigmoidf(float x) {
    return 1.f / (1.f + expf(-x));
}
__device__ __forceinline__ float2 bf2_to_f2(unsigned v) {
    union { unsigned u; float f; } a, b;
    a.u = v << 16;
    b.u = v & 0xffff0000u;
    return make_float2(a.f, b.f);
}
__device__ __forceinline__ unsigned f2_to_bf2(float x, float y) {
    union { float f; unsigned u; } a, b;
    a.f = x; b.f = y;
    unsigned lo = (a.u + 0x7fffu + ((a.u >> 16) & 1u)) >> 16;
    unsigned hi = ((b.u + 0x7fffu + ((b.u >> 16) & 1u)) >> 16) << 16;
    return lo | hi;
}

// ---------- embed: h = x @ W_embed + b ; writes f32 h, bf16 hb, masked zb[0:32] ----------
__global__ void embed_k(const float* __restrict__ x, const float* __restrict__ W,
                        const float* __restrict__ b, const int* __restrict__ ncnt,
                        float* __restrict__ h, unsigned* __restrict__ hb,
                        unsigned* __restrict__ zb) {
    __shared__ float xs[4][IN_DIM];
    int node0 = blockIdx.x * 4;
    int t = threadIdx.x;
    for (int idx = t; idx < 4 * IN_DIM; idx += 256) {
        int r = idx / IN_DIM, c = idx % IN_DIM;
        int node = node0 + r;
        xs[r][c] = (node < N_NODES) ? x[node * IN_DIM + c] : 0.f;
    }
    __syncthreads();
    int r = t >> 6, d = t & 63;
    int node = node0 + r;
    if (node >= N_NODES) return;
    float acc = b[d];
#pragma unroll 4
    for (int k = 0; k < IN_DIM; ++k) acc += xs[r][k] * W[k * 64 + d];
    h[node * 64 + d] = acc;
    float other = __shfl_xor(acc, 1);
    if ((d & 1) == 0) {
        unsigned pr = f2_to_bf2(acc, other);
        hb[node * 32 + (d >> 1)] = pr;
        zb[(size_t)node * KPAIRS + (d >> 1)] = (ncnt[node] > 0) ? pr : 0u;
    }
}

// ---------- hattr -> bf16 padded mirror ----------
__global__ void attrconv_k(const float* __restrict__ hattr, unsigned* __restrict__ hab) {
    int idx = blockIdx.x * 256 + threadIdx.x;
    if (idx >= N_HEDGES * ATTR_PAIRS) return;
    int e = idx / ATTR_PAIRS, p = idx - e * ATTR_PAIRS;
    int d0 = 2 * p, d1 = 2 * p + 1;
    float v0 = hattr[e * ATTR_DIM + d0];
    float v1 = (d1 < ATTR_DIM) ? hattr[e * ATTR_DIM + d1] : 0.f;
    hab[idx] = f2_to_bf2(v0, v1);
}

// ---------- weights -> Bt bf16 [l][c=128][k=192(96 pairs)] ----------
__global__ void btpack_k(const float* __restrict__ Wf, const float* __restrict__ Wc,
                         unsigned* __restrict__ Btb) {
    int idx = blockIdx.x * 256 + threadIdx.x;
    if (idx >= N_LAYERS * 128 * KPAIRS) return;
    int l = idx / (128 * KPAIRS);
    int rem = idx - l * 128 * KPAIRS;
    int c = rem / KPAIRS, p = rem - c * KPAIRS;
    int k0 = 2 * p, k1 = 2 * p + 1;
    const float* W = (c < 64) ? (Wf + (size_t)l * MSG_DIM * 64) : (Wc + (size_t)l * MSG_DIM * 64);
    int cc = c & 63;
    float v0 = (k0 < MSG_DIM) ? W[k0 * 64 + cc] : 0.f;
    float v1 = (k1 < MSG_DIM) ? W[k1 * 64 + cc] : 0.f;
    Btb[idx] = f2_to_bf2(v0, v1);
}

// ---------- sort S1: per-block bucket histogram ----------
__global__ void sorthist_k(const int* __restrict__ key, int* __restrict__ hist,
                           int kshift, int NB) {
    __shared__ int cnt[640];
    int blk = blockIdx.x;
    for (int i = threadIdx.x; i < NB; i += 256) cnt[i] = 0;
    __syncthreads();
    int base = blk * IPB;
    int end = min(base + IPB, N_INCID);
    for (int i = base + threadIdx.x; i < end; i += 256)
        atomicAdd(&cnt[key[i] >> kshift], 1);
    __syncthreads();
    for (int i = threadIdx.x; i < NB; i += 256) hist[blk * NB + i] = cnt[i];
}

// ---------- scan with bucket-major remap ----------
__global__ void scanR1_k(const int* __restrict__ in, int* __restrict__ out,
                         int* __restrict__ bsum, int n, int NB) {
    __shared__ int tmp[256];
    int gid = blockIdx.x * 256 + threadIdx.x;
    int v = 0;
    if (gid < n) {
        int bucket = gid / NBLK, blk = gid - bucket * NBLK;
        v = in[blk * NB + bucket];
    }
    tmp[threadIdx.x] = v;
    __syncthreads();
    for (int o = 1; o < 256; o <<= 1) {
        int t = (threadIdx.x >= o) ? tmp[threadIdx.x - o] : 0;
        __syncthreads();
        tmp[threadIdx.x] += t;
        __syncthreads();
    }
    if (gid < n) out[gid] = tmp[threadIdx.x] - v;
    if (threadIdx.x == 255) bsum[blockIdx.x] = tmp[255];
}

__global__ void scan2_k(int* __restrict__ bsum, int nb) {
    __shared__ int tmp[256];
    __shared__ int carry;
    if (threadIdx.x == 0) carry = 0;
    __syncthreads();
    for (int base = 0; base < nb; base += 256) {
        int gid = base + threadIdx.x;
        int v = (gid < nb) ? bsum[gid] : 0;
        tmp[threadIdx.x] = v;
        __syncthreads();
        for (int o = 1; o < 256; o <<= 1) {
            int t = (threadIdx.x >= o) ? tmp[threadIdx.x - o] : 0;
            __syncthreads();
            tmp[threadIdx.x] += t;
            __syncthreads();
        }
        if (gid < nb) bsum[gid] = tmp[threadIdx.x] - v + carry;
        __syncthreads();
        if (threadIdx.x == 0) carry += tmp[255];
        __syncthreads();
    }
}

__global__ void scan3_k(int* __restrict__ out, const int* __restrict__ bsum, int n) {
    int gid = blockIdx.x * 256 + threadIdx.x;
    if (gid < n) out[gid] += bsum[blockIdx.x];
}

// ---------- sort S3: scatter into bucketed staging ----------
__global__ void sortscat_k(const int* __restrict__ key, const int* __restrict__ val,
                           const int* __restrict__ soff, uint2* __restrict__ stage,
                           int kshift, int NB) {
    __shared__ int cur[640], bas[640];
    int blk = blockIdx.x;
    for (int i = threadIdx.x; i < NB; i += 256) {
        cur[i] = 0;
        bas[i] = soff[i * NBLK + blk];
    }
    __syncthreads();
    int base = blk * IPB;
    int end = min(base + IPB, N_INCID);
    for (int i = base + threadIdx.x; i < end; i += 256) {
        int k = key[i], b = k >> kshift;
        int d = bas[b] + atomicAdd(&cur[b], 1);
        stage[d] = make_uint2((unsigned)k, (unsigned)val[i]);
    }
}

// ---------- sort S4: fine counting-sort within bucket ----------
__global__ void sortfine_k(const uint2* __restrict__ stage, const int* __restrict__ soff,
                           int* __restrict__ csr, int* __restrict__ koff,
                           float* __restrict__ krcp, int* __restrict__ kcnt,
                           int kshift, int NB, int NKEYS, int nlog) {
    __shared__ int cnt[512], off[512], cur[512];
    int b = blockIdx.x;
    int KPB = 1 << kshift;
    int kbase = b << kshift;
    int base = soff[b * NBLK];
    int end = (b == NB - 1) ? N_INCID : soff[(b + 1) * NBLK];
    for (int i = threadIdx.x; i < KPB; i += 256) cnt[i] = 0;
    __syncthreads();
    for (int i = base + threadIdx.x; i < end; i += 256)
        atomicAdd(&cnt[(int)stage[i].x - kbase], 1);
    __syncthreads();
    if (threadIdx.x == 0) {
        int run = 0;
        for (int k = 0; k < KPB; ++k) { off[k] = run; run += cnt[k]; }
    }
    __syncthreads();
    for (int k = threadIdx.x; k < KPB; k += 256) {
        int gk = kbase + k;
        if (gk < NKEYS) {
            koff[gk] = base + off[k];
            krcp[gk] = 1.0f / (float)max(cnt[k], 1);
            kcnt[gk] = cnt[k];
        }
        cur[k] = 0;
    }
    __syncthreads();
    for (int i = base + threadIdx.x; i < end; i += 256) {
        uint2 it = stage[i];
        int lk = (int)it.x - kbase;
        int pos = base + off[lk] + atomicAdd(&cur[lk], 1);
        csr[pos] = (int)it.y;
    }
}

__global__ void sentinel_k(int* __restrict__ eoff, int* __restrict__ noff) {
    if (threadIdx.x == 0) eoff[N_HEDGES] = N_INCID;
    if (threadIdx.x == 1) noff[N_NODES] = N_INCID;
}

// ---------- per-hedge mean of member node bf16 rows (8-deep MLP) ----------
__global__ void hmean_k(const int* __restrict__ eoff, const int* __restrict__ csr_en,
                        const unsigned* __restrict__ hb, const float* __restrict__ ercp,
                        unsigned* __restrict__ hmean) {
    int idx = blockIdx.x * 256 + threadIdx.x;
    int e = idx >> 5, p = idx & 31;
    if (e >= N_HEDGES) return;
    int s = eoff[e], t = eoff[e + 1];
    float a0 = 0.f, a1 = 0.f;
    for (int base = s; base < t; base += 32) {
        int cnt = min(32, t - base);
        int myidx = (base + p < t) ? csr_en[base + p] : 0;
        for (int j = 0; j < cnt; j += 8) {
            unsigned v[8];
#pragma unroll
            for (int q = 0; q < 8; ++q) {
                int nq = __shfl(myidx, j + q, 32);
                v[q] = (j + q < cnt) ? hb[nq * 32 + p] : 0u;
            }
#pragma unroll
            for (int q = 0; q < 8; ++q) {
                float2 f = bf2_to_f2(v[q]);
                a0 += f.x; a1 += f.y;
            }
        }
    }
    float rc = ercp[e];
    hmean[e * 32 + p] = f2_to_bf2(a0 * rc, a1 * rc);
}

// ---------- per-node mean of hmean -> zb pairs 32..63 (bf16) ----------
__global__ void nodeh_k(const int* __restrict__ noff, const int* __restrict__ csr_ne,
                        const unsigned* __restrict__ hmean, const float* __restrict__ nrcp,
                        unsigned* __restrict__ zb) {
    int idx = blockIdx.x * 256 + threadIdx.x;
    int n = idx >> 5, p = idx & 31;
    if (n >= N_NODES) return;
    int s = noff[n], t = noff[n + 1];
    float a0 = 0.f, a1 = 0.f;
    for (int base = s; base < t; base += 32) {
        int cnt = min(32, t - base);
        int myidx = (base + p < t) ? csr_ne[base + p] : 0;
        for (int j = 0; j < cnt; j += 8) {
            unsigned v[8];
#pragma unroll
            for (int q = 0; q < 8; ++q) {
                int eq = __shfl(myidx, j + q, 32);
                v[q] = (j + q < cnt) ? hmean[eq * 32 + p] : 0u;
            }
#pragma unroll
            for (int q = 0; q < 8; ++q) {
                float2 f = bf2_to_f2(v[q]);
                a0 += f.x; a1 += f.y;
            }
        }
    }
    float rc = nrcp[n];
    zb[(size_t)n * KPAIRS + 32 + p] = f2_to_bf2(a0 * rc, a1 * rc);
}

// ---------- per-node mean of hedge_attr -> zb pairs 64..95 (one-time) ----------
__global__ void nodea_k(const int* __restrict__ noff, const int* __restrict__ csr_ne,
                        const unsigned* __restrict__ hab, const float* __restrict__ nrcp,
                        unsigned* __restrict__ zb) {
    int idx = blockIdx.x * 256 + threadIdx.x;
    int n = idx >> 5, p = idx & 31;
    if (n >= N_NODES) return;
    int s = noff[n], t = noff[n + 1];
    bool act = (p < ATTR_PAIRS);
    float a0 = 0.f, a1 = 0.f;
    for (int base = s; base < t; base += 32) {
        int cnt = min(32, t - base);
        int myidx = (base + p < t) ? csr_ne[base + p] : 0;
        for (int j = 0; j < cnt; j += 8) {
            unsigned v[8];
#pragma unroll
            for (int q = 0; q < 8; ++q) {
                int eq = __shfl(myidx, j + q, 32);
                v[q] = (act && (j + q < cnt)) ? hab[eq * ATTR_PAIRS + p] : 0u;
            }
#pragma unroll
            for (int q = 0; q < 8; ++q) {
                float2 f = bf2_to_f2(v[q]);
                a0 += f.x; a1 += f.y;
            }
        }
    }
    float rc = nrcp[n];
    unsigned pr = act ? f2_to_bf2(a0 * rc, a1 * rc) : 0u;
    zb[(size_t)n * KPAIRS + 64 + p] = pr;
}

// ---------- layer GEMM via MFMA: [64 nodes] x [K=192] @ [K=192 x 128] + fused epilogue ----------
__global__ void __launch_bounds__(256, 1)
layer_mfma_k(const unsigned* __restrict__ Btl, const float* __restrict__ bfv,
             const float* __restrict__ bcv, const int* __restrict__ ncnt,
             unsigned* __restrict__ zb, float* __restrict__ h,
             unsigned* __restrict__ hb) {
    __shared__ unsigned zsu[64][ZLDS];
    __shared__ unsigned btu[128][ZLDS];
    int node0 = blockIdx.x * 64;
    int t = threadIdx.x;

    // stage z tile (64 rows x 96 uints) via uint4
    {
        const uint4* zv = (const uint4*)zb;
        for (int idx = t; idx < 64 * 24; idx += 256) {
            int r = idx / 24, p4 = idx - r * 24;
            int node = node0 + r;
            uint4 v = make_uint4(0u, 0u, 0u, 0u);
            if (node < N_NODES) v = zv[(size_t)node * 24 + p4];
            *(uint4*)&zsu[r][p4 * 4] = v;
        }
        const uint4* bv = (const uint4*)Btl;
        for (int idx = t; idx < 128 * 24; idx += 256) {
            int c = idx / 24, p4 = idx - c * 24;
            *(uint4*)&btu[c][p4 * 4] = bv[c * 24 + p4];
        }
    }
    __syncthreads();

    int w = t >> 6, lane = t & 63;
    int row16 = lane & 15, kg = lane >> 4;
    f32x4 acc[8];
#pragma unroll
    for (int n = 0; n < 8; ++n) acc[n] = (f32x4){0.f, 0.f, 0.f, 0.f};

#pragma unroll
    for (int ks = 0; ks < 6; ++ks) {
        int pbase = ks * 16 + kg * 4;
        bf16x8 a = *(const bf16x8*)&zsu[w * 16 + row16][pbase];
#pragma unroll
        for (int n = 0; n < 8; ++n) {
            bf16x8 b = *(const bf16x8*)&btu[n * 16 + row16][pbase];
            acc[n] = __builtin_amdgcn_mfma_f32_16x16x32_bf16(a, b, acc[n], 0, 0, 0);
        }
    }

    // epilogue: f = cols 0..63 (acc 0..3), c = cols 64..127 (acc 4..7)
#pragma unroll
    for (int i = 0; i < 4; ++i) {
        int node = node0 + w * 16 + kg * 4 + i;
        if (node < N_NODES) {
            bool has = ncnt[node] > 0;
#pragma unroll
            for (int n = 0; n < 4; ++n) {
                int d = n * 16 + row16;
                float f = acc[n][i] + bfv[d];
                float c = acc[n + 4][i] + bcv[d];
                float hv = h[node * 64 + d];
                float nv = softplusf(sigmoidf(f) * softplusf(c) + hv);
                h[node * 64 + d] = nv;
                float other = __shfl_xor(nv, 1);
                if ((d & 1) == 0) {
                    unsigned pr = f2_to_bf2(nv, other);
                    hb[node * 32 + (d >> 1)] = pr;
                    zb[(size_t)node * KPAIRS + (d >> 1)] = has ? pr : 0u;
                }
            }
        }
    }
}

// ---------- per-graph boundaries ----------
__global__ void gstart_k(const int* __restrict__ batch, int* __restrict__ gstart) {
    int g = blockIdx.x * 256 + threadIdx.x;
    if (g > N_GRAPHS) return;
    int lo = 0, hi = N_NODES;
    while (lo < hi) {
        int mid = (lo + hi) >> 1;
        if (batch[mid] < g) lo = mid + 1; else hi = mid;
    }
    gstart[g] = lo;
}

// ---------- fused pool + proj + out ----------
__global__ void poolhead_k(const float* __restrict__ h, const int* __restrict__ gstart,
                           const float* __restrict__ Wp, const float* __restrict__ bp,
                           const float* __restrict__ Wo, const float* __restrict__ bo,
                           float* __restrict__ out) {
    __shared__ float partial[4][64];
    __shared__ float pm[64];
    __shared__ float pr[128];
    int g = blockIdx.x, t = threadIdx.x;
    int s = gstart[g], e = gstart[g + 1];
    int w = t >> 6, lane = t & 63;
    float acc = 0.f;
    for (int n = s + w; n < e; n += 4) acc += h[n * 64 + lane];
    partial[w][lane] = acc;
    __syncthreads();
    if (t < 64) {
        float c = fmaxf((float)(e - s), 1.0f);
        pm[t] = (partial[0][t] + partial[1][t] + partial[2][t] + partial[3][t]) / c;
    }
    __syncthreads();
    if (t < 128) {
        float a = bp[t];
#pragma unroll 4
        for (int k = 0; k < 64; ++k) a += pm[k] * Wp[k * HOUT_DIM + t];
        pr[t] = softplusf(a) * Wo[t];
    }
    __syncthreads();
    if (t < 64) {
        float v = pr[t] + pr[t + 64];
        for (int o = 32; o > 0; o >>= 1) v += __shfl_down(v, o);
        if (t == 0) out[g] = v + bo[0];
    }
}

extern "C" void kernel_launch(void* const* d_in, const int* in_sizes, int n_in,
                              void* d_out, int out_size, void* d_ws, size_t ws_size,
                              hipStream_t stream) {
    const float* x       = (const float*)d_in[0];
    const int*   inc_n   = (const int*)d_in[1];
    const int*   inc_e   = (const int*)d_in[2];
    const float* hattr   = (const float*)d_in[3];
    const int*   batch   = (const int*)d_in[4];
    const float* W_embed = (const float*)d_in[5];
    const float* b_embed = (const float*)d_in[6];
    const float* Wf      = (const float*)d_in[7];
    const float* bf      = (const float*)d_in[8];
    const float* Wc      = (const float*)d_in[9];
    const float* bc      = (const float*)d_in[10];
    const float* W_proj  = (const float*)d_in[11];
    const float* b_proj  = (const float*)d_in[12];
    const float* W_out   = (const float*)d_in[13];
    const float* b_out   = (const float*)d_in[14];
    float* out = (float*)d_out;

    char* ws = (char*)d_ws;
    size_t off = 0;
    auto alloc = [&](size_t bytes) {
        void* p = ws + off;
        off = (off + bytes + 255) & ~(size_t)255;
        return p;
    };
    float*    h      = (float*)alloc((size_t)N_NODES * 64 * 4);
    unsigned* hb     = (unsigned*)alloc((size_t)N_NODES * 32 * 4);
    unsigned* hmean  = (unsigned*)alloc((size_t)N_HEDGES * 32 * 4);  // aliases sort staging
    unsigned* zb     = (unsigned*)alloc((size_t)N_NODES * KPAIRS * 4);
    unsigned* hab    = (unsigned*)alloc((size_t)N_HEDGES * ATTR_PAIRS * 4);
    unsigned* Btb    = (unsigned*)alloc((size_t)N_LAYERS * 128 * KPAIRS * 4);
    int*      ncnt   = (int*)alloc((size_t)N_NODES * 4);
    int*      ecnt   = (int*)alloc((size_t)N_HEDGES * 4);
    float*    nrcp   = (float*)alloc((size_t)N_NODES * 4);
    float*    ercp   = (float*)alloc((size_t)N_HEDGES * 4);
    int*      eoff   = (int*)alloc((size_t)(N_HEDGES + 1) * 4);
    int*      noff   = (int*)alloc((size_t)(N_NODES + 1) * 4);
    int*      csr_en = (int*)alloc((size_t)N_INCID * 4);
    int*      csr_ne = (int*)alloc((size_t)N_INCID * 4);
    int*      hist   = (int*)alloc((size_t)NB_E * NBLK * 4);
    int*      soff   = (int*)alloc((size_t)NB_E * NBLK * 4);
    int*      bsum   = (int*)alloc((size_t)2048 * 4);
    int*      gstart = (int*)alloc((size_t)(N_GRAPHS + 1) * 4);
    uint2*    stage  = (uint2*)hmean;

    // ---- hedge-side sort: key=inc_e, val=inc_n -> csr_en, eoff, ercp ----
    {
        int nlog = NB_E * NBLK;
        int nsb = (nlog + 255) / 256;
        sorthist_k<<<NBLK, 256, 0, stream>>>(inc_e, hist, ESHIFT, NB_E);
        scanR1_k<<<nsb, 256, 0, stream>>>(hist, soff, bsum, nlog, NB_E);
        scan2_k<<<1, 256, 0, stream>>>(bsum, nsb);
        scan3_k<<<nsb, 256, 0, stream>>>(soff, bsum, nlog);
        sortscat_k<<<NBLK, 256, 0, stream>>>(inc_e, inc_n, soff, stage, ESHIFT, NB_E);
        sortfine_k<<<NB_E, 256, 0, stream>>>(stage, soff, csr_en, eoff, ercp, ecnt,
                                             ESHIFT, NB_E, N_HEDGES, nlog);
    }
    // ---- node-side sort: key=inc_n, val=inc_e -> csr_ne, noff, nrcp, ncnt ----
    {
        int nlog = NB_N * NBLK;
        int nsb = (nlog + 255) / 256;
        sorthist_k<<<NBLK, 256, 0, stream>>>(inc_n, hist, NSHIFT, NB_N);
        scanR1_k<<<nsb, 256, 0, stream>>>(hist, soff, bsum, nlog, NB_N);
        scan2_k<<<1, 256, 0, stream>>>(bsum, nsb);
        scan3_k<<<nsb, 256, 0, stream>>>(soff, bsum, nlog);
        sortscat_k<<<NBLK, 256, 0, stream>>>(inc_n, inc_e, soff, stage, NSHIFT, NB_N);
        sortfine_k<<<NB_N, 256, 0, stream>>>(stage, soff, csr_ne, noff, nrcp, ncnt,
                                             NSHIFT, NB_N, N_NODES, nlog);
    }
    sentinel_k<<<1, 64, 0, stream>>>(eoff, noff);

    embed_k<<<(N_NODES + 3) / 4, 256, 0, stream>>>(x, W_embed, b_embed, ncnt, h, hb, zb);
    attrconv_k<<<(N_HEDGES * ATTR_PAIRS + 255) / 256, 256, 0, stream>>>(hattr, hab);
    btpack_k<<<(N_LAYERS * 128 * KPAIRS + 255) / 256, 256, 0, stream>>>(Wf, Wc, Btb);
    nodea_k<<<(N_NODES * 32) / 256, 256, 0, stream>>>(noff, csr_ne, hab, nrcp, zb);

    for (int l = 0; l < N_LAYERS; ++l) {
        hmean_k<<<(N_HEDGES * 32) / 256, 256, 0, stream>>>(eoff, csr_en, hb, ercp, hmean);
        nodeh_k<<<(N_NODES * 32) / 256, 256, 0, stream>>>(noff, csr_ne, hmean, nrcp, zb);
        layer_mfma_k<<<(N_NODES + 63) / 64, 256, 0, stream>>>(Btb + (size_t)l * 128 * KPAIRS,
                                                              bf + l * 64, bc + l * 64,
                                                              ncnt, zb, h, hb);
    }
    gstart_k<<<(N_GRAPHS + 1 + 255) / 256, 256, 0, stream>>>(batch, gstart);
    poolhead_k<<<N_GRAPHS, 256, 0, stream>>>(h, gstart, W_proj, b_proj, W_out, b_out, out);
}

// Round 7
// 770.021 us; speedup vs baseline: 5.2604x; 1.0578x over previous
//
#include <hip/hip_runtime.h>
#include <hip/hip_bf16.h>

#define N_NODES 100000
#define N_INCID 2000000
#define N_HEDGES 300000
#define IN_DIM 92
#define H_DIM 64
#define ATTR_DIM 35
#define ATTR_PAIRS 18
#define HOUT_DIM 128
#define N_GRAPHS 512
#define N_LAYERS 3
#define MSG_DIM 163
#define KPAIRS 96        // layer K padded to 192 bf16 = 96 uint pairs
#define ZLDS 100         // layer LDS row stride in uints
#define EPAIRS 48        // embed K padded to 96 bf16 = 48 pairs
#define ELDS 50          // embed LDS row stride in uints

// sort geometry
#define IPB 8192
#define NBLK 245
#define ESHIFT 9
#define NB_E 586
#define NSHIFT 8
#define NB_N 391

typedef short bf16x8 __attribute__((ext_vector_type(8)));
typedef float f32x4 __attribute__((ext_vector_type(4)));

__device__ __forceinline__ float softplusf(float x) {
    return fmaxf(x, 0.f) + log1pf(expf(-fabsf(x)));
}
__device__ __forceinline__ float sigmoidf(float x) {
    return 1.f / (1.f + expf(-x));
}
__device__ __forceinline__ float2 bf2_to_f2(unsigned v) {
    union { unsigned u; float f; } a, b;
    a.u = v << 16;
    b.u = v & 0xffff0000u;
    return make_float2(a.f, b.f);
}
__device__ __forceinline__ unsigned f2_to_bf2(float x, float y) {
    union { float f; unsigned u; } a, b;
    a.f = x; b.f = y;
    unsigned lo = (a.u + 0x7fffu + ((a.u >> 16) & 1u)) >> 16;
    unsigned hi = ((b.u + 0x7fffu + ((b.u >> 16) & 1u)) >> 16) << 16;
    return lo | hi;
}

// ---------- W_embed -> bf16 Bt [c=64][p=48] ----------
__global__ void embpack_k(const float* __restrict__ W, unsigned* __restrict__ BtE) {
    int idx = blockIdx.x * 256 + threadIdx.x;
    if (idx >= 64 * EPAIRS) return;
    int c = idx / EPAIRS, p = idx - c * EPAIRS;
    int k0 = 2 * p, k1 = 2 * p + 1;
    float v0 = (k0 < IN_DIM) ? W[k0 * 64 + c] : 0.f;
    float v1 = (k1 < IN_DIM) ? W[k1 * 64 + c] : 0.f;
    BtE[idx] = f2_to_bf2(v0, v1);
}

// ---------- embed via MFMA: h = x @ W_embed + b ; fused h/hb/zb epilogue ----------
__global__ void __launch_bounds__(256, 1)
embed_mfma_k(const float* __restrict__ x, const unsigned* __restrict__ BtE,
             const float* __restrict__ be, const int* __restrict__ ncnt,
             float* __restrict__ h, unsigned* __restrict__ hb,
             unsigned* __restrict__ zb) {
    __shared__ unsigned zsu[64][ELDS];
    __shared__ unsigned btu[64][ELDS];
    int node0 = blockIdx.x * 64;
    int t = threadIdx.x;
    for (int idx = t; idx < 64 * EPAIRS; idx += 256) {
        int r = idx / EPAIRS, p = idx - r * EPAIRS;
        int node = node0 + r;
        unsigned pr = 0u;
        if (node < N_NODES && p < 46) {
            float2 f = *(const float2*)(x + (size_t)node * IN_DIM + 2 * p);
            pr = f2_to_bf2(f.x, f.y);
        }
        zsu[r][p] = pr;
    }
    for (int idx = t; idx < 64 * EPAIRS; idx += 256) {
        int c = idx / EPAIRS, p = idx - c * EPAIRS;
        btu[c][p] = BtE[idx];
    }
    __syncthreads();
    int w = t >> 6, lane = t & 63, row16 = lane & 15, kg = lane >> 4;
    f32x4 acc[4];
#pragma unroll
    for (int n = 0; n < 4; ++n) acc[n] = (f32x4){0.f, 0.f, 0.f, 0.f};
#pragma unroll
    for (int ks = 0; ks < 3; ++ks) {
        int pbase = ks * 16 + kg * 4;
        bf16x8 a = *(const bf16x8*)&zsu[w * 16 + row16][pbase];
#pragma unroll
        for (int n = 0; n < 4; ++n) {
            bf16x8 b = *(const bf16x8*)&btu[n * 16 + row16][pbase];
            acc[n] = __builtin_amdgcn_mfma_f32_16x16x32_bf16(a, b, acc[n], 0, 0, 0);
        }
    }
#pragma unroll
    for (int i = 0; i < 4; ++i) {
        int node = node0 + w * 16 + kg * 4 + i;
        if (node < N_NODES) {
            bool has = ncnt[node] > 0;
#pragma unroll
            for (int n = 0; n < 4; ++n) {
                int d = n * 16 + row16;
                float nv = acc[n][i] + be[d];
                h[node * 64 + d] = nv;
                float other = __shfl_xor(nv, 1);
                if ((d & 1) == 0) {
                    unsigned pr = f2_to_bf2(nv, other);
                    hb[node * 32 + (d >> 1)] = pr;
                    zb[(size_t)node * KPAIRS + (d >> 1)] = has ? pr : 0u;
                }
            }
        }
    }
}

// ---------- hattr -> bf16 padded mirror ----------
__global__ void attrconv_k(const float* __restrict__ hattr, unsigned* __restrict__ hab) {
    int idx = blockIdx.x * 256 + threadIdx.x;
    if (idx >= N_HEDGES * ATTR_PAIRS) return;
    int e = idx / ATTR_PAIRS, p = idx - e * ATTR_PAIRS;
    int d0 = 2 * p, d1 = 2 * p + 1;
    float v0 = hattr[e * ATTR_DIM + d0];
    float v1 = (d1 < ATTR_DIM) ? hattr[e * ATTR_DIM + d1] : 0.f;
    hab[idx] = f2_to_bf2(v0, v1);
}

// ---------- layer weights -> Bt bf16 [l][c=128][k pairs=96] ----------
__global__ void btpack_k(const float* __restrict__ Wf, const float* __restrict__ Wc,
                         unsigned* __restrict__ Btb) {
    int idx = blockIdx.x * 256 + threadIdx.x;
    if (idx >= N_LAYERS * 128 * KPAIRS) return;
    int l = idx / (128 * KPAIRS);
    int rem = idx - l * 128 * KPAIRS;
    int c = rem / KPAIRS, p = rem - c * KPAIRS;
    int k0 = 2 * p, k1 = 2 * p + 1;
    const float* W = (c < 64) ? (Wf + (size_t)l * MSG_DIM * 64) : (Wc + (size_t)l * MSG_DIM * 64);
    int cc = c & 63;
    float v0 = (k0 < MSG_DIM) ? W[k0 * 64 + cc] : 0.f;
    float v1 = (k1 < MSG_DIM) ? W[k1 * 64 + cc] : 0.f;
    Btb[idx] = f2_to_bf2(v0, v1);
}

// ---------- sort S1 ----------
__global__ void sorthist_k(const int* __restrict__ key, int* __restrict__ hist,
                           int kshift, int NB) {
    __shared__ int cnt[640];
    int blk = blockIdx.x;
    for (int i = threadIdx.x; i < NB; i += 256) cnt[i] = 0;
    __syncthreads();
    int base = blk * IPB;
    int end = min(base + IPB, N_INCID);
    for (int i = base + threadIdx.x; i < end; i += 256)
        atomicAdd(&cnt[key[i] >> kshift], 1);
    __syncthreads();
    for (int i = threadIdx.x; i < NB; i += 256) hist[blk * NB + i] = cnt[i];
}

// ---------- scan with bucket-major remap ----------
__global__ void scanR1_k(const int* __restrict__ in, int* __restrict__ out,
                         int* __restrict__ bsum, int n, int NB) {
    __shared__ int tmp[256];
    int gid = blockIdx.x * 256 + threadIdx.x;
    int v = 0;
    if (gid < n) {
        int bucket = gid / NBLK, blk = gid - bucket * NBLK;
        v = in[blk * NB + bucket];
    }
    tmp[threadIdx.x] = v;
    __syncthreads();
    for (int o = 1; o < 256; o <<= 1) {
        int t = (threadIdx.x >= o) ? tmp[threadIdx.x - o] : 0;
        __syncthreads();
        tmp[threadIdx.x] += t;
        __syncthreads();
    }
    if (gid < n) out[gid] = tmp[threadIdx.x] - v;
    if (threadIdx.x == 255) bsum[blockIdx.x] = tmp[255];
}

__global__ void scan2_k(int* __restrict__ bsum, int nb) {
    __shared__ int tmp[256];
    __shared__ int carry;
    if (threadIdx.x == 0) carry = 0;
    __syncthreads();
    for (int base = 0; base < nb; base += 256) {
        int gid = base + threadIdx.x;
        int v = (gid < nb) ? bsum[gid] : 0;
        tmp[threadIdx.x] = v;
        __syncthreads();
        for (int o = 1; o < 256; o <<= 1) {
            int t = (threadIdx.x >= o) ? tmp[threadIdx.x - o] : 0;
            __syncthreads();
            tmp[threadIdx.x] += t;
            __syncthreads();
        }
        if (gid < nb) bsum[gid] = tmp[threadIdx.x] - v + carry;
        __syncthreads();
        if (threadIdx.x == 0) carry += tmp[255];
        __syncthreads();
    }
}

__global__ void scan3_k(int* __restrict__ out, const int* __restrict__ bsum, int n) {
    int gid = blockIdx.x * 256 + threadIdx.x;
    if (gid < n) out[gid] += bsum[blockIdx.x];
}

// ---------- sort S3 ----------
__global__ void sortscat_k(const int* __restrict__ key, const int* __restrict__ val,
                           const int* __restrict__ soff, uint2* __restrict__ stage,
                           int kshift, int NB) {
    __shared__ int cur[640], bas[640];
    int blk = blockIdx.x;
    for (int i = threadIdx.x; i < NB; i += 256) {
        cur[i] = 0;
        bas[i] = soff[i * NBLK + blk];
    }
    __syncthreads();
    int base = blk * IPB;
    int end = min(base + IPB, N_INCID);
    for (int i = base + threadIdx.x; i < end; i += 256) {
        int k = key[i], b = k >> kshift;
        int d = bas[b] + atomicAdd(&cur[b], 1);
        stage[d] = make_uint2((unsigned)k, (unsigned)val[i]);
    }
}

// ---------- sort S4 ----------
__global__ void sortfine_k(const uint2* __restrict__ stage, const int* __restrict__ soff,
                           int* __restrict__ csr, int* __restrict__ koff,
                           float* __restrict__ krcp, int* __restrict__ kcnt,
                           int kshift, int NB, int NKEYS, int nlog) {
    __shared__ int cnt[512], off[512], cur[512];
    int b = blockIdx.x;
    int KPB = 1 << kshift;
    int kbase = b << kshift;
    int base = soff[b * NBLK];
    int end = (b == NB - 1) ? N_INCID : soff[(b + 1) * NBLK];
    for (int i = threadIdx.x; i < KPB; i += 256) cnt[i] = 0;
    __syncthreads();
    for (int i = base + threadIdx.x; i < end; i += 256)
        atomicAdd(&cnt[(int)stage[i].x - kbase], 1);
    __syncthreads();
    if (threadIdx.x == 0) {
        int run = 0;
        for (int k = 0; k < KPB; ++k) { off[k] = run; run += cnt[k]; }
    }
    __syncthreads();
    for (int k = threadIdx.x; k < KPB; k += 256) {
        int gk = kbase + k;
        if (gk < NKEYS) {
            koff[gk] = base + off[k];
            krcp[gk] = 1.0f / (float)max(cnt[k], 1);
            kcnt[gk] = cnt[k];
        }
        cur[k] = 0;
    }
    __syncthreads();
    for (int i = base + threadIdx.x; i < end; i += 256) {
        uint2 it = stage[i];
        int lk = (int)it.x - kbase;
        int pos = base + off[lk] + atomicAdd(&cur[lk], 1);
        csr[pos] = (int)it.y;
    }
}

__global__ void sentinel_k(int* __restrict__ eoff, int* __restrict__ noff) {
    if (threadIdx.x == 0) eoff[N_HEDGES] = N_INCID;
    if (threadIdx.x == 1) noff[N_NODES] = N_INCID;
}

// ---------- per-hedge mean: uint2/lane, 16 lanes/row, 16 members per 8-load flight ----------
__global__ void hmean_k(const int* __restrict__ eoff, const int* __restrict__ csr_en,
                        const uint2* __restrict__ hbv, const float* __restrict__ ercp,
                        uint2* __restrict__ hmv) {
    int idx = blockIdx.x * 256 + threadIdx.x;
    int e = idx >> 5, l = idx & 31;
    if (e >= N_HEDGES) return;
    int sub = l >> 4, q = l & 15;
    int s = eoff[e], t = eoff[e + 1];
    float a0 = 0.f, a1 = 0.f, a2 = 0.f, a3 = 0.f;
    for (int base = s; base < t; base += 32) {
        int cnt = min(32, t - base);
        int myidx = (base + l < t) ? csr_en[base + l] : 0;
        for (int j = 0; j < cnt; j += 16) {
            uint2 v[8];
#pragma unroll
            for (int w = 0; w < 8; ++w) {
                int mem = j + 2 * w + sub;
                int nq = __shfl(myidx, mem, 32);
                v[w] = (mem < cnt) ? hbv[nq * 16 + q] : make_uint2(0u, 0u);
            }
#pragma unroll
            for (int w = 0; w < 8; ++w) {
                float2 f0 = bf2_to_f2(v[w].x), f1 = bf2_to_f2(v[w].y);
                a0 += f0.x; a1 += f0.y; a2 += f1.x; a3 += f1.y;
            }
        }
    }
    a0 += __shfl_xor(a0, 16);
    a1 += __shfl_xor(a1, 16);
    a2 += __shfl_xor(a2, 16);
    a3 += __shfl_xor(a3, 16);
    if (sub == 0) {
        float rc = ercp[e];
        hmv[e * 16 + q] = make_uint2(f2_to_bf2(a0 * rc, a1 * rc), f2_to_bf2(a2 * rc, a3 * rc));
    }
}

// ---------- per-node mean of hmean -> zb pairs 32..63 ----------
__global__ void nodeh_k(const int* __restrict__ noff, const int* __restrict__ csr_ne,
                        const uint2* __restrict__ hmv, const float* __restrict__ nrcp,
                        uint2* __restrict__ zbv) {
    int idx = blockIdx.x * 256 + threadIdx.x;
    int n = idx >> 5, l = idx & 31;
    if (n >= N_NODES) return;
    int sub = l >> 4, q = l & 15;
    int s = noff[n], t = noff[n + 1];
    float a0 = 0.f, a1 = 0.f, a2 = 0.f, a3 = 0.f;
    for (int base = s; base < t; base += 32) {
        int cnt = min(32, t - base);
        int myidx = (base + l < t) ? csr_ne[base + l] : 0;
        for (int j = 0; j < cnt; j += 16) {
            uint2 v[8];
#pragma unroll
            for (int w = 0; w < 8; ++w) {
                int mem = j + 2 * w + sub;
                int eq = __shfl(myidx, mem, 32);
                v[w] = (mem < cnt) ? hmv[eq * 16 + q] : make_uint2(0u, 0u);
            }
#pragma unroll
            for (int w = 0; w < 8; ++w) {
                float2 f0 = bf2_to_f2(v[w].x), f1 = bf2_to_f2(v[w].y);
                a0 += f0.x; a1 += f0.y; a2 += f1.x; a3 += f1.y;
            }
        }
    }
    a0 += __shfl_xor(a0, 16);
    a1 += __shfl_xor(a1, 16);
    a2 += __shfl_xor(a2, 16);
    a3 += __shfl_xor(a3, 16);
    if (sub == 0) {
        float rc = nrcp[n];
        zbv[(size_t)n * (KPAIRS / 2) + 16 + q] =
            make_uint2(f2_to_bf2(a0 * rc, a1 * rc), f2_to_bf2(a2 * rc, a3 * rc));
    }
}

// ---------- per-node mean of hedge_attr -> zb pairs 64..95 (one-time) ----------
__global__ void nodea_k(const int* __restrict__ noff, const int* __restrict__ csr_ne,
                        const uint2* __restrict__ habv, const float* __restrict__ nrcp,
                        uint2* __restrict__ zbv) {
    int idx = blockIdx.x * 256 + threadIdx.x;
    int n = idx >> 5, l = idx & 31;
    if (n >= N_NODES) return;
    int sub = l >> 4, q = l & 15;
    bool act = (q < ATTR_PAIRS / 2);  // 9 uint2 per attr row
    int s = noff[n], t = noff[n + 1];
    float a0 = 0.f, a1 = 0.f, a2 = 0.f, a3 = 0.f;
    for (int base = s; base < t; base += 32) {
        int cnt = min(32, t - base);
        int myidx = (base + l < t) ? csr_ne[base + l] : 0;
        for (int j = 0; j < cnt; j += 16) {
            uint2 v[8];
#pragma unroll
            for (int w = 0; w < 8; ++w) {
                int mem = j + 2 * w + sub;
                int eq = __shfl(myidx, mem, 32);
                v[w] = (act && mem < cnt) ? habv[eq * (ATTR_PAIRS / 2) + q] : make_uint2(0u, 0u);
            }
#pragma unroll
            for (int w = 0; w < 8; ++w) {
                float2 f0 = bf2_to_f2(v[w].x), f1 = bf2_to_f2(v[w].y);
                a0 += f0.x; a1 += f0.y; a2 += f1.x; a3 += f1.y;
            }
        }
    }
    a0 += __shfl_xor(a0, 16);
    a1 += __shfl_xor(a1, 16);
    a2 += __shfl_xor(a2, 16);
    a3 += __shfl_xor(a3, 16);
    if (sub == 0) {
        float rc = nrcp[n];
        uint2 pr = act ? make_uint2(f2_to_bf2(a0 * rc, a1 * rc), f2_to_bf2(a2 * rc, a3 * rc))
                       : make_uint2(0u, 0u);
        zbv[(size_t)n * (KPAIRS / 2) + 32 + q] = pr;
    }
}

// ---------- layer GEMM via MFMA + fused epilogue ----------
__global__ void __launch_bounds__(256, 1)
layer_mfma_k(const unsigned* __restrict__ Btl, const float* __restrict__ bfv,
             const float* __restrict__ bcv, const int* __restrict__ ncnt,
             unsigned* __restrict__ zb, float* __restrict__ h,
             unsigned* __restrict__ hb) {
    __shared__ unsigned zsu[64][ZLDS];
    __shared__ unsigned btu[128][ZLDS];
    int node0 = blockIdx.x * 64;
    int t = threadIdx.x;
    {
        const uint4* zv = (const uint4*)zb;
        for (int idx = t; idx < 64 * 24; idx += 256) {
            int r = idx / 24, p4 = idx - r * 24;
            int node = node0 + r;
            uint4 v = make_uint4(0u, 0u, 0u, 0u);
            if (node < N_NODES) v = zv[(size_t)node * 24 + p4];
            *(uint4*)&zsu[r][p4 * 4] = v;
        }
        const uint4* bv = (const uint4*)Btl;
        for (int idx = t; idx < 128 * 24; idx += 256) {
            int c = idx / 24, p4 = idx - c * 24;
            *(uint4*)&btu[c][p4 * 4] = bv[c * 24 + p4];
        }
    }
    __syncthreads();

    int w = t >> 6, lane = t & 63;
    int row16 = lane & 15, kg = lane >> 4;
    f32x4 acc[8];
#pragma unroll
    for (int n = 0; n < 8; ++n) acc[n] = (f32x4){0.f, 0.f, 0.f, 0.f};

#pragma unroll
    for (int ks = 0; ks < 6; ++ks) {
        int pbase = ks * 16 + kg * 4;
        bf16x8 a = *(const bf16x8*)&zsu[w * 16 + row16][pbase];
#pragma unroll
        for (int n = 0; n < 8; ++n) {
            bf16x8 b = *(const bf16x8*)&btu[n * 16 + row16][pbase];
            acc[n] = __builtin_amdgcn_mfma_f32_16x16x32_bf16(a, b, acc[n], 0, 0, 0);
        }
    }

#pragma unroll
    for (int i = 0; i < 4; ++i) {
        int node = node0 + w * 16 + kg * 4 + i;
        if (node < N_NODES) {
            bool has = ncnt[node] > 0;
#pragma unroll
            for (int n = 0; n < 4; ++n) {
                int d = n * 16 + row16;
                float f = acc[n][i] + bfv[d];
                float c = acc[n + 4][i] + bcv[d];
                float hv = h[node * 64 + d];
                float nv = softplusf(sigmoidf(f) * softplusf(c) + hv);
                h[node * 64 + d] = nv;
                float other = __shfl_xor(nv, 1);
                if ((d & 1) == 0) {
                    unsigned pr = f2_to_bf2(nv, other);
                    hb[node * 32 + (d >> 1)] = pr;
                    zb[(size_t)node * KPAIRS + (d >> 1)] = has ? pr : 0u;
                }
            }
        }
    }
}

// ---------- per-graph boundaries ----------
__global__ void gstart_k(const int* __restrict__ batch, int* __restrict__ gstart) {
    int g = blockIdx.x * 256 + threadIdx.x;
    if (g > N_GRAPHS) return;
    int lo = 0, hi = N_NODES;
    while (lo < hi) {
        int mid = (lo + hi) >> 1;
        if (batch[mid] < g) lo = mid + 1; else hi = mid;
    }
    gstart[g] = lo;
}

// ---------- fused pool + proj + out ----------
__global__ void poolhead_k(const float* __restrict__ h, const int* __restrict__ gstart,
                           const float* __restrict__ Wp, const float* __restrict__ bp,
                           const float* __restrict__ Wo, const float* __restrict__ bo,
                           float* __restrict__ out) {
    __shared__ float partial[4][64];
    __shared__ float pm[64];
    __shared__ float pr[128];
    int g = blockIdx.x, t = threadIdx.x;
    int s = gstart[g], e = gstart[g + 1];
    int w = t >> 6, lane = t & 63;
    float acc = 0.f;
    for (int n = s + w; n < e; n += 4) acc += h[n * 64 + lane];
    partial[w][lane] = acc;
    __syncthreads();
    if (t < 64) {
        float c = fmaxf((float)(e - s), 1.0f);
        pm[t] = (partial[0][t] + partial[1][t] + partial[2][t] + partial[3][t]) / c;
    }
    __syncthreads();
    if (t < 128) {
        float a = bp[t];
#pragma unroll 4
        for (int k = 0; k < 64; ++k) a += pm[k] * Wp[k * HOUT_DIM + t];
        pr[t] = softplusf(a) * Wo[t];
    }
    __syncthreads();
    if (t < 64) {
        float v = pr[t] + pr[t + 64];
        for (int o = 32; o > 0; o >>= 1) v += __shfl_down(v, o);
        if (t == 0) out[g] = v + bo[0];
    }
}

extern "C" void kernel_launch(void* const* d_in, const int* in_sizes, int n_in,
                              void* d_out, int out_size, void* d_ws, size_t ws_size,
                              hipStream_t stream) {
    const float* x       = (const float*)d_in[0];
    const int*   inc_n   = (const int*)d_in[1];
    const int*   inc_e   = (const int*)d_in[2];
    const float* hattr   = (const float*)d_in[3];
    const int*   batch   = (const int*)d_in[4];
    const float* W_embed = (const float*)d_in[5];
    const float* b_embed = (const float*)d_in[6];
    const float* Wf      = (const float*)d_in[7];
    const float* bf      = (const float*)d_in[8];
    const float* Wc      = (const float*)d_in[9];
    const float* bc      = (const float*)d_in[10];
    const float* W_proj  = (const float*)d_in[11];
    const float* b_proj  = (const float*)d_in[12];
    const float* W_out   = (const float*)d_in[13];
    const float* b_out   = (const float*)d_in[14];
    float* out = (float*)d_out;

    char* ws = (char*)d_ws;
    size_t off = 0;
    auto alloc = [&](size_t bytes) {
        void* p = ws + off;
        off = (off + bytes + 255) & ~(size_t)255;
        return p;
    };
    float*    h      = (float*)alloc((size_t)N_NODES * 64 * 4);
    unsigned* hb     = (unsigned*)alloc((size_t)N_NODES * 32 * 4);
    unsigned* hmean  = (unsigned*)alloc((size_t)N_HEDGES * 32 * 4);  // aliases sort staging
    unsigned* zb     = (unsigned*)alloc((size_t)N_NODES * KPAIRS * 4);
    unsigned* hab    = (unsigned*)alloc((size_t)N_HEDGES * ATTR_PAIRS * 4);
    unsigned* Btb    = (unsigned*)alloc((size_t)N_LAYERS * 128 * KPAIRS * 4);
    unsigned* BtE    = (unsigned*)alloc((size_t)64 * EPAIRS * 4);
    int*      ncnt   = (int*)alloc((size_t)N_NODES * 4);
    int*      ecnt   = (int*)alloc((size_t)N_HEDGES * 4);
    float*    nrcp   = (float*)alloc((size_t)N_NODES * 4);
    float*    ercp   = (float*)alloc((size_t)N_HEDGES * 4);
    int*      eoff   = (int*)alloc((size_t)(N_HEDGES + 1) * 4);
    int*      noff   = (int*)alloc((size_t)(N_NODES + 1) * 4);
    int*      csr_en = (int*)alloc((size_t)N_INCID * 4);
    int*      csr_ne = (int*)alloc((size_t)N_INCID * 4);
    int*      hist   = (int*)alloc((size_t)NB_E * NBLK * 4);
    int*      soff   = (int*)alloc((size_t)NB_E * NBLK * 4);
    int*      bsum   = (int*)alloc((size_t)2048 * 4);
    int*      gstart = (int*)alloc((size_t)(N_GRAPHS + 1) * 4);
    uint2*    stage  = (uint2*)hmean;

    // ---- hedge-side sort ----
    {
        int nlog = NB_E * NBLK;
        int nsb = (nlog + 255) / 256;
        sorthist_k<<<NBLK, 256, 0, stream>>>(inc_e, hist, ESHIFT, NB_E);
        scanR1_k<<<nsb, 256, 0, stream>>>(hist, soff, bsum, nlog, NB_E);
        scan2_k<<<1, 256, 0, stream>>>(bsum, nsb);
        scan3_k<<<nsb, 256, 0, stream>>>(soff, bsum, nlog);
        sortscat_k<<<NBLK, 256, 0, stream>>>(inc_e, inc_n, soff, stage, ESHIFT, NB_E);
        sortfine_k<<<NB_E, 256, 0, stream>>>(stage, soff, csr_en, eoff, ercp, ecnt,
                                             ESHIFT, NB_E, N_HEDGES, nlog);
    }
    // ---- node-side sort ----
    {
        int nlog = NB_N * NBLK;
        int nsb = (nlog + 255) / 256;
        sorthist_k<<<NBLK, 256, 0, stream>>>(inc_n, hist, NSHIFT, NB_N);
        scanR1_k<<<nsb, 256, 0, stream>>>(hist, soff, bsum, nlog, NB_N);
        scan2_k<<<1, 256, 0, stream>>>(bsum, nsb);
        scan3_k<<<nsb, 256, 0, stream>>>(soff, bsum, nlog);
        sortscat_k<<<NBLK, 256, 0, stream>>>(inc_n, inc_e, soff, stage, NSHIFT, NB_N);
        sortfine_k<<<NB_N, 256, 0, stream>>>(stage, soff, csr_ne, noff, nrcp, ncnt,
                                             NSHIFT, NB_N, N_NODES, nlog);
    }
    sentinel_k<<<1, 64, 0, stream>>>(eoff, noff);

    embpack_k<<<(64 * EPAIRS + 255) / 256, 256, 0, stream>>>(W_embed, BtE);
    embed_mfma_k<<<(N_NODES + 63) / 64, 256, 0, stream>>>(x, BtE, b_embed, ncnt, h, hb, zb);
    attrconv_k<<<(N_HEDGES * ATTR_PAIRS + 255) / 256, 256, 0, stream>>>(hattr, hab);
    btpack_k<<<(N_LAYERS * 128 * KPAIRS + 255) / 256, 256, 0, stream>>>(Wf, Wc, Btb);
    nodea_k<<<(N_NODES * 32) / 256, 256, 0, stream>>>(noff, csr_ne, (const uint2*)hab, nrcp,
                                                      (uint2*)zb);

    for (int l = 0; l < N_LAYERS; ++l) {
        hmean_k<<<(N_HEDGES * 32) / 256, 256, 0, stream>>>(eoff, csr_en, (const uint2*)hb, ercp,
                                                           (uint2*)hmean);
        nodeh_k<<<(N_NODES * 32) / 256, 256, 0, stream>>>(noff, csr_ne, (const uint2*)hmean, nrcp,
                                                          (uint2*)zb);
        layer_mfma_k<<<(N_NODES + 63) / 64, 256, 0, stream>>>(Btb + (size_t)l * 128 * KPAIRS,
                                                              bf + l * 64, bc + l * 64,
                                                              ncnt, zb, h, hb);
    }
    gstart_k<<<(N_GRAPHS + 1 + 255) / 256, 256, 0, stream>>>(batch, gstart);
    poolhead_k<<<N_GRAPHS, 256, 0, stream>>>(h, gstart, W_proj, b_proj, W_out, b_out, out);
}

// Round 8
// 639.151 us; speedup vs baseline: 6.3376x; 1.2048x over previous
//
#include <hip/hip_runtime.h>
#include <hip/hip_bf16.h>

#define N_NODES 100000
#define N_INCID 2000000
#define N_HEDGES 300000
#define IN_DIM 92
#define H_DIM 64
#define ATTR_DIM 35
#define ATTR_PAIRS 18
#define HOUT_DIM 128
#define N_GRAPHS 512
#define N_LAYERS 3
#define MSG_DIM 163
#define KPAIRS 96        // layer K padded to 192 bf16 = 96 uint pairs
#define ZLDS 100         // layer LDS row stride in uints
#define EPAIRS 48        // embed K padded to 96 bf16 = 48 pairs
#define ELDS 50          // embed LDS row stride in uints

// sort geometry
#define IPB 8192
#define NBLK 245
#define ESHIFT 9
#define NB_E 586
#define NSHIFT 8
#define NB_N 391

typedef short bf16x8 __attribute__((ext_vector_type(8)));
typedef float f32x4 __attribute__((ext_vector_type(4)));

__device__ __forceinline__ float softplusf(float x) {
    // fast: native v_exp/v_log; |err| ~1e-6, fine vs 8.8e-3 threshold
    return fmaxf(x, 0.f) + __logf(1.f + __expf(-fabsf(x)));
}
__device__ __forceinline__ float sigmoidf(float x) {
    return __builtin_amdgcn_rcpf(1.f + __expf(-x));
}
__device__ __forceinline__ float2 bf2_to_f2(unsigned v) {
    union { unsigned u; float f; } a, b;
    a.u = v << 16;
    b.u = v & 0xffff0000u;
    return make_float2(a.f, b.f);
}
__device__ __forceinline__ unsigned f2_to_bf2(float x, float y) {
    union { float f; unsigned u; } a, b;
    a.f = x; b.f = y;
    unsigned lo = (a.u + 0x7fffu + ((a.u >> 16) & 1u)) >> 16;
    unsigned hi = ((b.u + 0x7fffu + ((b.u >> 16) & 1u)) >> 16) << 16;
    return lo | hi;
}

// ---------- W_embed -> bf16 Bt [c=64][p=48] ----------
__global__ void embpack_k(const float* __restrict__ W, unsigned* __restrict__ BtE) {
    int idx = blockIdx.x * 256 + threadIdx.x;
    if (idx >= 64 * EPAIRS) return;
    int c = idx / EPAIRS, p = idx - c * EPAIRS;
    int k0 = 2 * p, k1 = 2 * p + 1;
    float v0 = (k0 < IN_DIM) ? W[k0 * 64 + c] : 0.f;
    float v1 = (k1 < IN_DIM) ? W[k1 * 64 + c] : 0.f;
    BtE[idx] = f2_to_bf2(v0, v1);
}

// ---------- embed via MFMA ----------
__global__ void __launch_bounds__(256)
embed_mfma_k(const float* __restrict__ x, const unsigned* __restrict__ BtE,
             const float* __restrict__ be, const int* __restrict__ ncnt,
             float* __restrict__ h, unsigned* __restrict__ hb,
             unsigned* __restrict__ zb) {
    __shared__ unsigned zsu[64][ELDS];
    __shared__ unsigned btu[64][ELDS];
    int node0 = blockIdx.x * 64;
    int t = threadIdx.x;
    for (int idx = t; idx < 64 * EPAIRS; idx += 256) {
        int r = idx / EPAIRS, p = idx - r * EPAIRS;
        int node = node0 + r;
        unsigned pr = 0u;
        if (node < N_NODES && p < 46) {
            float2 f = *(const float2*)(x + (size_t)node * IN_DIM + 2 * p);
            pr = f2_to_bf2(f.x, f.y);
        }
        zsu[r][p] = pr;
    }
    for (int idx = t; idx < 64 * EPAIRS; idx += 256) {
        int c = idx / EPAIRS, p = idx - c * EPAIRS;
        btu[c][p] = BtE[idx];
    }
    __syncthreads();
    int w = t >> 6, lane = t & 63, row16 = lane & 15, kg = lane >> 4;
    f32x4 acc[4];
#pragma unroll
    for (int n = 0; n < 4; ++n) acc[n] = (f32x4){0.f, 0.f, 0.f, 0.f};
#pragma unroll
    for (int ks = 0; ks < 3; ++ks) {
        int pbase = ks * 16 + kg * 4;
        bf16x8 a = *(const bf16x8*)&zsu[w * 16 + row16][pbase];
#pragma unroll
        for (int n = 0; n < 4; ++n) {
            bf16x8 b = *(const bf16x8*)&btu[n * 16 + row16][pbase];
            acc[n] = __builtin_amdgcn_mfma_f32_16x16x32_bf16(a, b, acc[n], 0, 0, 0);
        }
    }
#pragma unroll
    for (int i = 0; i < 4; ++i) {
        int node = node0 + w * 16 + kg * 4 + i;
        if (node < N_NODES) {
            bool has = ncnt[node] > 0;
#pragma unroll
            for (int n = 0; n < 4; ++n) {
                int d = n * 16 + row16;
                float nv = acc[n][i] + be[d];
                h[node * 64 + d] = nv;
                float other = __shfl_xor(nv, 1);
                if ((d & 1) == 0) {
                    unsigned pr = f2_to_bf2(nv, other);
                    hb[node * 32 + (d >> 1)] = pr;
                    zb[(size_t)node * KPAIRS + (d >> 1)] = has ? pr : 0u;
                }
            }
        }
    }
}

// ---------- hattr -> bf16 padded mirror ----------
__global__ void attrconv_k(const float* __restrict__ hattr, unsigned* __restrict__ hab) {
    int idx = blockIdx.x * 256 + threadIdx.x;
    if (idx >= N_HEDGES * ATTR_PAIRS) return;
    int e = idx / ATTR_PAIRS, p = idx - e * ATTR_PAIRS;
    int d0 = 2 * p, d1 = 2 * p + 1;
    float v0 = hattr[e * ATTR_DIM + d0];
    float v1 = (d1 < ATTR_DIM) ? hattr[e * ATTR_DIM + d1] : 0.f;
    hab[idx] = f2_to_bf2(v0, v1);
}

// ---------- layer weights -> Bt bf16 [l][c=128][k pairs=96] ----------
__global__ void btpack_k(const float* __restrict__ Wf, const float* __restrict__ Wc,
                         unsigned* __restrict__ Btb) {
    int idx = blockIdx.x * 256 + threadIdx.x;
    if (idx >= N_LAYERS * 128 * KPAIRS) return;
    int l = idx / (128 * KPAIRS);
    int rem = idx - l * 128 * KPAIRS;
    int c = rem / KPAIRS, p = rem - c * KPAIRS;
    int k0 = 2 * p, k1 = 2 * p + 1;
    const float* W = (c < 64) ? (Wf + (size_t)l * MSG_DIM * 64) : (Wc + (size_t)l * MSG_DIM * 64);
    int cc = c & 63;
    float v0 = (k0 < MSG_DIM) ? W[k0 * 64 + cc] : 0.f;
    float v1 = (k1 < MSG_DIM) ? W[k1 * 64 + cc] : 0.f;
    Btb[idx] = f2_to_bf2(v0, v1);
}

// ---------- sort S1 ----------
__global__ void sorthist_k(const int* __restrict__ key, int* __restrict__ hist,
                           int kshift, int NB) {
    __shared__ int cnt[640];
    int blk = blockIdx.x;
    for (int i = threadIdx.x; i < NB; i += 256) cnt[i] = 0;
    __syncthreads();
    int base = blk * IPB;
    int end = min(base + IPB, N_INCID);
    for (int i = base + threadIdx.x; i < end; i += 256)
        atomicAdd(&cnt[key[i] >> kshift], 1);
    __syncthreads();
    for (int i = threadIdx.x; i < NB; i += 256) hist[blk * NB + i] = cnt[i];
}

// ---------- scan with bucket-major remap ----------
__global__ void scanR1_k(const int* __restrict__ in, int* __restrict__ out,
                         int* __restrict__ bsum, int n, int NB) {
    __shared__ int tmp[256];
    int gid = blockIdx.x * 256 + threadIdx.x;
    int v = 0;
    if (gid < n) {
        int bucket = gid / NBLK, blk = gid - bucket * NBLK;
        v = in[blk * NB + bucket];
    }
    tmp[threadIdx.x] = v;
    __syncthreads();
    for (int o = 1; o < 256; o <<= 1) {
        int t = (threadIdx.x >= o) ? tmp[threadIdx.x - o] : 0;
        __syncthreads();
        tmp[threadIdx.x] += t;
        __syncthreads();
    }
    if (gid < n) out[gid] = tmp[threadIdx.x] - v;
    if (threadIdx.x == 255) bsum[blockIdx.x] = tmp[255];
}

__global__ void scan2_k(int* __restrict__ bsum, int nb) {
    __shared__ int tmp[256];
    __shared__ int carry;
    if (threadIdx.x == 0) carry = 0;
    __syncthreads();
    for (int base = 0; base < nb; base += 256) {
        int gid = base + threadIdx.x;
        int v = (gid < nb) ? bsum[gid] : 0;
        tmp[threadIdx.x] = v;
        __syncthreads();
        for (int o = 1; o < 256; o <<= 1) {
            int t = (threadIdx.x >= o) ? tmp[threadIdx.x - o] : 0;
            __syncthreads();
            tmp[threadIdx.x] += t;
            __syncthreads();
        }
        if (gid < nb) bsum[gid] = tmp[threadIdx.x] - v + carry;
        __syncthreads();
        if (threadIdx.x == 0) carry += tmp[255];
        __syncthreads();
    }
}

__global__ void scan3_k(int* __restrict__ out, const int* __restrict__ bsum, int n) {
    int gid = blockIdx.x * 256 + threadIdx.x;
    if (gid < n) out[gid] += bsum[blockIdx.x];
}

// ---------- sort S3 ----------
__global__ void sortscat_k(const int* __restrict__ key, const int* __restrict__ val,
                           const int* __restrict__ soff, uint2* __restrict__ stage,
                           int kshift, int NB) {
    __shared__ int cur[640], bas[640];
    int blk = blockIdx.x;
    for (int i = threadIdx.x; i < NB; i += 256) {
        cur[i] = 0;
        bas[i] = soff[i * NBLK + blk];
    }
    __syncthreads();
    int base = blk * IPB;
    int end = min(base + IPB, N_INCID);
    for (int i = base + threadIdx.x; i < end; i += 256) {
        int k = key[i], b = k >> kshift;
        int d = bas[b] + atomicAdd(&cur[b], 1);
        stage[d] = make_uint2((unsigned)k, (unsigned)val[i]);
    }
}

// ---------- sort S4 ----------
__global__ void sortfine_k(const uint2* __restrict__ stage, const int* __restrict__ soff,
                           int* __restrict__ csr, int* __restrict__ koff,
                           float* __restrict__ krcp, int* __restrict__ kcnt,
                           int kshift, int NB, int NKEYS, int nlog) {
    __shared__ int cnt[512], off[512], cur[512];
    int b = blockIdx.x;
    int KPB = 1 << kshift;
    int kbase = b << kshift;
    int base = soff[b * NBLK];
    int end = (b == NB - 1) ? N_INCID : soff[(b + 1) * NBLK];
    for (int i = threadIdx.x; i < KPB; i += 256) cnt[i] = 0;
    __syncthreads();
    for (int i = base + threadIdx.x; i < end; i += 256)
        atomicAdd(&cnt[(int)stage[i].x - kbase], 1);
    __syncthreads();
    if (threadIdx.x == 0) {
        int run = 0;
        for (int k = 0; k < KPB; ++k) { off[k] = run; run += cnt[k]; }
    }
    __syncthreads();
    for (int k = threadIdx.x; k < KPB; k += 256) {
        int gk = kbase + k;
        if (gk < NKEYS) {
            koff[gk] = base + off[k];
            krcp[gk] = 1.0f / (float)max(cnt[k], 1);
            kcnt[gk] = cnt[k];
        }
        cur[k] = 0;
    }
    __syncthreads();
    for (int i = base + threadIdx.x; i < end; i += 256) {
        uint2 it = stage[i];
        int lk = (int)it.x - kbase;
        int pos = base + off[lk] + atomicAdd(&cur[lk], 1);
        csr[pos] = (int)it.y;
    }
}

__global__ void sentinel_k(int* __restrict__ eoff, int* __restrict__ noff) {
    if (threadIdx.x == 0) eoff[N_HEDGES] = N_INCID;
    if (threadIdx.x == 1) noff[N_NODES] = N_INCID;
}

// ---------- per-hedge mean: uint2/lane, 16 lanes/row ----------
__global__ void hmean_k(const int* __restrict__ eoff, const int* __restrict__ csr_en,
                        const uint2* __restrict__ hbv, const float* __restrict__ ercp,
                        uint2* __restrict__ hmv) {
    int idx = blockIdx.x * 256 + threadIdx.x;
    int e = idx >> 5, l = idx & 31;
    if (e >= N_HEDGES) return;
    int sub = l >> 4, q = l & 15;
    int s = eoff[e], t = eoff[e + 1];
    float a0 = 0.f, a1 = 0.f, a2 = 0.f, a3 = 0.f;
    for (int base = s; base < t; base += 32) {
        int cnt = min(32, t - base);
        int myidx = (base + l < t) ? csr_en[base + l] : 0;
        for (int j = 0; j < cnt; j += 16) {
            uint2 v[8];
#pragma unroll
            for (int w = 0; w < 8; ++w) {
                int mem = j + 2 * w + sub;
                int nq = __shfl(myidx, mem, 32);
                v[w] = (mem < cnt) ? hbv[nq * 16 + q] : make_uint2(0u, 0u);
            }
#pragma unroll
            for (int w = 0; w < 8; ++w) {
                float2 f0 = bf2_to_f2(v[w].x), f1 = bf2_to_f2(v[w].y);
                a0 += f0.x; a1 += f0.y; a2 += f1.x; a3 += f1.y;
            }
        }
    }
    a0 += __shfl_xor(a0, 16);
    a1 += __shfl_xor(a1, 16);
    a2 += __shfl_xor(a2, 16);
    a3 += __shfl_xor(a3, 16);
    if (sub == 0) {
        float rc = ercp[e];
        hmv[e * 16 + q] = make_uint2(f2_to_bf2(a0 * rc, a1 * rc), f2_to_bf2(a2 * rc, a3 * rc));
    }
}

// ---------- per-node mean of hmean -> zb pairs 32..63 ----------
__global__ void nodeh_k(const int* __restrict__ noff, const int* __restrict__ csr_ne,
                        const uint2* __restrict__ hmv, const float* __restrict__ nrcp,
                        uint2* __restrict__ zbv) {
    int idx = blockIdx.x * 256 + threadIdx.x;
    int n = idx >> 5, l = idx & 31;
    if (n >= N_NODES) return;
    int sub = l >> 4, q = l & 15;
    int s = noff[n], t = noff[n + 1];
    float a0 = 0.f, a1 = 0.f, a2 = 0.f, a3 = 0.f;
    for (int base = s; base < t; base += 32) {
        int cnt = min(32, t - base);
        int myidx = (base + l < t) ? csr_ne[base + l] : 0;
        for (int j = 0; j < cnt; j += 16) {
            uint2 v[8];
#pragma unroll
            for (int w = 0; w < 8; ++w) {
                int mem = j + 2 * w + sub;
                int eq = __shfl(myidx, mem, 32);
                v[w] = (mem < cnt) ? hmv[eq * 16 + q] : make_uint2(0u, 0u);
            }
#pragma unroll
            for (int w = 0; w < 8; ++w) {
                float2 f0 = bf2_to_f2(v[w].x), f1 = bf2_to_f2(v[w].y);
                a0 += f0.x; a1 += f0.y; a2 += f1.x; a3 += f1.y;
            }
        }
    }
    a0 += __shfl_xor(a0, 16);
    a1 += __shfl_xor(a1, 16);
    a2 += __shfl_xor(a2, 16);
    a3 += __shfl_xor(a3, 16);
    if (sub == 0) {
        float rc = nrcp[n];
        zbv[(size_t)n * (KPAIRS / 2) + 16 + q] =
            make_uint2(f2_to_bf2(a0 * rc, a1 * rc), f2_to_bf2(a2 * rc, a3 * rc));
    }
}

// ---------- per-node mean of hedge_attr -> zb pairs 64..95 (one-time) ----------
__global__ void nodea_k(const int* __restrict__ noff, const int* __restrict__ csr_ne,
                        const uint2* __restrict__ habv, const float* __restrict__ nrcp,
                        uint2* __restrict__ zbv) {
    int idx = blockIdx.x * 256 + threadIdx.x;
    int n = idx >> 5, l = idx & 31;
    if (n >= N_NODES) return;
    int sub = l >> 4, q = l & 15;
    bool act = (q < ATTR_PAIRS / 2);
    int s = noff[n], t = noff[n + 1];
    float a0 = 0.f, a1 = 0.f, a2 = 0.f, a3 = 0.f;
    for (int base = s; base < t; base += 32) {
        int cnt = min(32, t - base);
        int myidx = (base + l < t) ? csr_ne[base + l] : 0;
        for (int j = 0; j < cnt; j += 16) {
            uint2 v[8];
#pragma unroll
            for (int w = 0; w < 8; ++w) {
                int mem = j + 2 * w + sub;
                int eq = __shfl(myidx, mem, 32);
                v[w] = (act && mem < cnt) ? habv[eq * (ATTR_PAIRS / 2) + q] : make_uint2(0u, 0u);
            }
#pragma unroll
            for (int w = 0; w < 8; ++w) {
                float2 f0 = bf2_to_f2(v[w].x), f1 = bf2_to_f2(v[w].y);
                a0 += f0.x; a1 += f0.y; a2 += f1.x; a3 += f1.y;
            }
        }
    }
    a0 += __shfl_xor(a0, 16);
    a1 += __shfl_xor(a1, 16);
    a2 += __shfl_xor(a2, 16);
    a3 += __shfl_xor(a3, 16);
    if (sub == 0) {
        float rc = nrcp[n];
        uint2 pr = act ? make_uint2(f2_to_bf2(a0 * rc, a1 * rc), f2_to_bf2(a2 * rc, a3 * rc))
                       : make_uint2(0u, 0u);
        zbv[(size_t)n * (KPAIRS / 2) + 32 + q] = pr;
    }
}

// ---------- layer GEMM via MFMA; B in registers (weights L1/L2-hot), A in LDS ----------
// wave w owns col blocks {w, w+4}: f cols [16w,16w+16), c cols [64+16w, 64+16w+16)
__global__ void __launch_bounds__(256)
layer_mfma_k(const unsigned* __restrict__ Btl, const float* __restrict__ bfv,
             const float* __restrict__ bcv, const int* __restrict__ ncnt,
             unsigned* __restrict__ zb, float* __restrict__ h,
             unsigned* __restrict__ hb) {
    __shared__ unsigned zsu[64][ZLDS];
    int node0 = blockIdx.x * 64;
    int t = threadIdx.x;
    int w = t >> 6, lane = t & 63;
    int row16 = lane & 15, kg = lane >> 4;

    // B fragments -> registers (independent of LDS staging; 12 x 16B per lane)
    uint4 bregF[6], bregC[6];
    {
        const uint4* bv = (const uint4*)Btl;
        int colF = w * 16 + row16;
        int colC = colF + 64;
#pragma unroll
        for (int ks = 0; ks < 6; ++ks) {
            bregF[ks] = bv[colF * 24 + ks * 4 + kg];
            bregC[ks] = bv[colC * 24 + ks * 4 + kg];
        }
    }
    // stage A tile (64 rows x 96 uints)
    {
        const uint4* zv = (const uint4*)zb;
        for (int idx = t; idx < 64 * 24; idx += 256) {
            int r = idx / 24, p4 = idx - r * 24;
            int node = node0 + r;
            uint4 v = make_uint4(0u, 0u, 0u, 0u);
            if (node < N_NODES) v = zv[(size_t)node * 24 + p4];
            *(uint4*)&zsu[r][p4 * 4] = v;
        }
    }
    __syncthreads();

    f32x4 accF[4], accC[4];
#pragma unroll
    for (int n = 0; n < 4; ++n) {
        accF[n] = (f32x4){0.f, 0.f, 0.f, 0.f};
        accC[n] = (f32x4){0.f, 0.f, 0.f, 0.f};
    }

#pragma unroll
    for (int ks = 0; ks < 6; ++ks) {
        int pbase = ks * 16 + kg * 4;
        bf16x8 bF = *(const bf16x8*)&bregF[ks];
        bf16x8 bC = *(const bf16x8*)&bregC[ks];
#pragma unroll
        for (int rb = 0; rb < 4; ++rb) {
            bf16x8 a = *(const bf16x8*)&zsu[rb * 16 + row16][pbase];
            accF[rb] = __builtin_amdgcn_mfma_f32_16x16x32_bf16(a, bF, accF[rb], 0, 0, 0);
            accC[rb] = __builtin_amdgcn_mfma_f32_16x16x32_bf16(a, bC, accC[rb], 0, 0, 0);
        }
    }

    int d = w * 16 + row16;
    float bfd = bfv[d], bcd = bcv[d];
#pragma unroll
    for (int rb = 0; rb < 4; ++rb) {
#pragma unroll
        for (int i = 0; i < 4; ++i) {
            int node = node0 + rb * 16 + kg * 4 + i;
            if (node < N_NODES) {
                bool has = ncnt[node] > 0;
                float f = accF[rb][i] + bfd;
                float c = accC[rb][i] + bcd;
                float hv = h[node * 64 + d];
                float nv = softplusf(sigmoidf(f) * softplusf(c) + hv);
                h[node * 64 + d] = nv;
                float other = __shfl_xor(nv, 1);
                if ((d & 1) == 0) {
                    unsigned pr = f2_to_bf2(nv, other);
                    hb[node * 32 + (d >> 1)] = pr;
                    zb[(size_t)node * KPAIRS + (d >> 1)] = has ? pr : 0u;
                }
            }
        }
    }
}

// ---------- per-graph boundaries ----------
__global__ void gstart_k(const int* __restrict__ batch, int* __restrict__ gstart) {
    int g = blockIdx.x * 256 + threadIdx.x;
    if (g > N_GRAPHS) return;
    int lo = 0, hi = N_NODES;
    while (lo < hi) {
        int mid = (lo + hi) >> 1;
        if (batch[mid] < g) lo = mid + 1; else hi = mid;
    }
    gstart[g] = lo;
}

// ---------- fused pool + proj + out ----------
__global__ void poolhead_k(const float* __restrict__ h, const int* __restrict__ gstart,
                           const float* __restrict__ Wp, const float* __restrict__ bp,
                           const float* __restrict__ Wo, const float* __restrict__ bo,
                           float* __restrict__ out) {
    __shared__ float partial[4][64];
    __shared__ float pm[64];
    __shared__ float pr[128];
    int g = blockIdx.x, t = threadIdx.x;
    int s = gstart[g], e = gstart[g + 1];
    int w = t >> 6, lane = t & 63;
    float acc = 0.f;
    for (int n = s + w; n < e; n += 4) acc += h[n * 64 + lane];
    partial[w][lane] = acc;
    __syncthreads();
    if (t < 64) {
        float c = fmaxf((float)(e - s), 1.0f);
        pm[t] = (partial[0][t] + partial[1][t] + partial[2][t] + partial[3][t]) / c;
    }
    __syncthreads();
    if (t < 128) {
        float a = bp[t];
#pragma unroll 4
        for (int k = 0; k < 64; ++k) a += pm[k] * Wp[k * HOUT_DIM + t];
        pr[t] = softplusf(a) * Wo[t];
    }
    __syncthreads();
    if (t < 64) {
        float v = pr[t] + pr[t + 64];
        for (int o = 32; o > 0; o >>= 1) v += __shfl_down(v, o);
        if (t == 0) out[g] = v + bo[0];
    }
}

extern "C" void kernel_launch(void* const* d_in, const int* in_sizes, int n_in,
                              void* d_out, int out_size, void* d_ws, size_t ws_size,
                              hipStream_t stream) {
    const float* x       = (const float*)d_in[0];
    const int*   inc_n   = (const int*)d_in[1];
    const int*   inc_e   = (const int*)d_in[2];
    const float* hattr   = (const float*)d_in[3];
    const int*   batch   = (const int*)d_in[4];
    const float* W_embed = (const float*)d_in[5];
    const float* b_embed = (const float*)d_in[6];
    const float* Wf      = (const float*)d_in[7];
    const float* bf      = (const float*)d_in[8];
    const float* Wc      = (const float*)d_in[9];
    const float* bc      = (const float*)d_in[10];
    const float* W_proj  = (const float*)d_in[11];
    const float* b_proj  = (const float*)d_in[12];
    const float* W_out   = (const float*)d_in[13];
    const float* b_out   = (const float*)d_in[14];
    float* out = (float*)d_out;

    char* ws = (char*)d_ws;
    size_t off = 0;
    auto alloc = [&](size_t bytes) {
        void* p = ws + off;
        off = (off + bytes + 255) & ~(size_t)255;
        return p;
    };
    float*    h      = (float*)alloc((size_t)N_NODES * 64 * 4);
    unsigned* hb     = (unsigned*)alloc((size_t)N_NODES * 32 * 4);
    unsigned* hmean  = (unsigned*)alloc((size_t)N_HEDGES * 32 * 4);  // aliases sort staging
    unsigned* zb     = (unsigned*)alloc((size_t)N_NODES * KPAIRS * 4);
    unsigned* hab    = (unsigned*)alloc((size_t)N_HEDGES * ATTR_PAIRS * 4);
    unsigned* Btb    = (unsigned*)alloc((size_t)N_LAYERS * 128 * KPAIRS * 4);
    unsigned* BtE    = (unsigned*)alloc((size_t)64 * EPAIRS * 4);
    int*      ncnt   = (int*)alloc((size_t)N_NODES * 4);
    int*      ecnt   = (int*)alloc((size_t)N_HEDGES * 4);
    float*    nrcp   = (float*)alloc((size_t)N_NODES * 4);
    float*    ercp   = (float*)alloc((size_t)N_HEDGES * 4);
    int*      eoff   = (int*)alloc((size_t)(N_HEDGES + 1) * 4);
    int*      noff   = (int*)alloc((size_t)(N_NODES + 1) * 4);
    int*      csr_en = (int*)alloc((size_t)N_INCID * 4);
    int*      csr_ne = (int*)alloc((size_t)N_INCID * 4);
    int*      hist   = (int*)alloc((size_t)NB_E * NBLK * 4);
    int*      soff   = (int*)alloc((size_t)NB_E * NBLK * 4);
    int*      bsum   = (int*)alloc((size_t)2048 * 4);
    int*      gstart = (int*)alloc((size_t)(N_GRAPHS + 1) * 4);
    uint2*    stage  = (uint2*)hmean;

    // ---- hedge-side sort ----
    {
        int nlog = NB_E * NBLK;
        int nsb = (nlog + 255) / 256;
        sorthist_k<<<NBLK, 256, 0, stream>>>(inc_e, hist, ESHIFT, NB_E);
        scanR1_k<<<nsb, 256, 0, stream>>>(hist, soff, bsum, nlog, NB_E);
        scan2_k<<<1, 256, 0, stream>>>(bsum, nsb);
        scan3_k<<<nsb, 256, 0, stream>>>(soff, bsum, nlog);
        sortscat_k<<<NBLK, 256, 0, stream>>>(inc_e, inc_n, soff, stage, ESHIFT, NB_E);
        sortfine_k<<<NB_E, 256, 0, stream>>>(stage, soff, csr_en, eoff, ercp, ecnt,
                                             ESHIFT, NB_E, N_HEDGES, nlog);
    }
    // ---- node-side sort ----
    {
        int nlog = NB_N * NBLK;
        int nsb = (nlog + 255) / 256;
        sorthist_k<<<NBLK, 256, 0, stream>>>(inc_n, hist, NSHIFT, NB_N);
        scanR1_k<<<nsb, 256, 0, stream>>>(hist, soff, bsum, nlog, NB_N);
        scan2_k<<<1, 256, 0, stream>>>(bsum, nsb);
        scan3_k<<<nsb, 256, 0, stream>>>(soff, bsum, nlog);
        sortscat_k<<<NBLK, 256, 0, stream>>>(inc_n, inc_e, soff, stage, NSHIFT, NB_N);
        sortfine_k<<<NB_N, 256, 0, stream>>>(stage, soff, csr_ne, noff, nrcp, ncnt,
                                             NSHIFT, NB_N, N_NODES, nlog);
    }
    sentinel_k<<<1, 64, 0, stream>>>(eoff, noff);

    embpack_k<<<(64 * EPAIRS + 255) / 256, 256, 0, stream>>>(W_embed, BtE);
    embed_mfma_k<<<(N_NODES + 63) / 64, 256, 0, stream>>>(x, BtE, b_embed, ncnt, h, hb, zb);
    attrconv_k<<<(N_HEDGES * ATTR_PAIRS + 255) / 256, 256, 0, stream>>>(hattr, hab);
    btpack_k<<<(N_LAYERS * 128 * KPAIRS + 255) / 256, 256, 0, stream>>>(Wf, Wc, Btb);
    nodea_k<<<(N_NODES * 32) / 256, 256, 0, stream>>>(noff, csr_ne, (const uint2*)hab, nrcp,
                                                      (uint2*)zb);

    for (int l = 0; l < N_LAYERS; ++l) {
        hmean_k<<<(N_HEDGES * 32) / 256, 256, 0, stream>>>(eoff, csr_en, (const uint2*)hb, ercp,
                                                           (uint2*)hmean);
        nodeh_k<<<(N_NODES * 32) / 256, 256, 0, stream>>>(noff, csr_ne, (const uint2*)hmean, nrcp,
                                                          (uint2*)zb);
        layer_mfma_k<<<(N_NODES + 63) / 64, 256, 0, stream>>>(Btb + (size_t)l * 128 * KPAIRS,
                                                              bf + l * 64, bc + l * 64,
                                                              ncnt, zb, h, hb);
    }
    gstart_k<<<(N_GRAPHS + 1 + 255) / 256, 256, 0, stream>>>(batch, gstart);
    poolhead_k<<<N_GRAPHS, 256, 0, stream>>>(h, gstart, W_proj, b_proj, W_out, b_out, out);
}